// Round 1
// baseline (1143.676 us; speedup 1.0000x reference)
//
#include <hip/hip_runtime.h>
#include <math.h>

#define FDIM 128

// ---------------- CSR build ----------------

__global__ void k_histo(const int* __restrict__ col, int* __restrict__ cnt, int nE) {
  int stride = gridDim.x * blockDim.x;
  for (int e = blockIdx.x * blockDim.x + threadIdx.x; e < nE; e += stride)
    atomicAdd(&cnt[col[e]], 1);
}

// 1024-element chunk exclusive scan (256 threads, 4 elems each)
__global__ void k_scan_chunks(const int* __restrict__ cnt, int* __restrict__ offs,
                              int* __restrict__ bsums, int n) {
  __shared__ int lds[1024];
  int base = blockIdx.x * 1024;
  for (int i = threadIdx.x; i < 1024; i += 256) {
    int g = base + i;
    lds[i] = (g < n) ? cnt[g] : 0;
  }
  __syncthreads();
  for (int off = 1; off < 1024; off <<= 1) {
    int v[4];
#pragma unroll
    for (int k = 0; k < 4; ++k) {
      int i = threadIdx.x + k * 256;
      v[k] = (i >= off) ? lds[i - off] : 0;
    }
    __syncthreads();
#pragma unroll
    for (int k = 0; k < 4; ++k) {
      int i = threadIdx.x + k * 256;
      lds[i] += v[k];
    }
    __syncthreads();
  }
  for (int i = threadIdx.x; i < 1024; i += 256) {
    int g = base + i;
    if (g < n) offs[g] = (i == 0) ? 0 : lds[i - 1];
  }
  if (threadIdx.x == 0) bsums[blockIdx.x] = lds[1023];
}

// exclusive scan of chunk sums (nchunks <= 256) in one block
__global__ void k_scan_bsums(int* __restrict__ bsums, int nchunks) {
  __shared__ int lds[256];
  int t = threadIdx.x;
  int v = (t < nchunks) ? bsums[t] : 0;
  lds[t] = v;
  __syncthreads();
  for (int off = 1; off < 256; off <<= 1) {
    int x = (t >= off) ? lds[t - off] : 0;
    __syncthreads();
    lds[t] += x;
    __syncthreads();
  }
  if (t < nchunks) bsums[t] = (t == 0) ? 0 : lds[t - 1];
}

__global__ void k_finalize(int* __restrict__ offs, const int* __restrict__ bsums,
                           int* __restrict__ cur, float* __restrict__ dinv,
                           const int* __restrict__ cnt, int n) {
  int i = blockIdx.x * blockDim.x + threadIdx.x;
  if (i >= n) return;
  int o = offs[i] + bsums[i >> 10];
  offs[i] = o;
  cur[i] = o;
  dinv[i] = rsqrtf((float)(cnt[i] + 1));  // +1 = self loop; deg >= 1 always
}

__global__ void k_scatter(const int* __restrict__ row, const int* __restrict__ col,
                          int* __restrict__ cur, int* __restrict__ srcs, int nE) {
  int stride = gridDim.x * blockDim.x;
  for (int e = blockIdx.x * blockDim.x + threadIdx.x; e < nE; e += stride) {
    int c = col[e];
    int p = atomicAdd(&cur[c], 1);
    srcs[p] = row[e];
  }
}

// ---------------- GEMM [n,128] x [128,128], epilogue *dinv[row] ----------------
// 256 threads/block, 128 rows/block: thread t -> rows 2*(t>>2), cols {(t&3)*4 + jv*16 + 0..3}
__global__ __launch_bounds__(256, 2)
void k_gemm_scale(const float* __restrict__ in, const float* __restrict__ W,
                  const float* __restrict__ dinv, float* __restrict__ out, int n) {
  __shared__ float wl[FDIM * FDIM];
  {
    const float4* W4 = (const float4*)W;
    float4* wl4 = (float4*)wl;
    for (int i = threadIdx.x; i < FDIM * FDIM / 4; i += 256) wl4[i] = W4[i];
  }
  __syncthreads();
  int t = threadIdx.x;
  int r0 = blockIdx.x * 128 + ((t >> 2) << 1);
  if (r0 >= n) return;
  int lc = t & 3;
  bool two = (r0 + 1 < n);
  const float4* a4 = (const float4*)(in + (size_t)r0 * FDIM);
  const float4* b4 = (const float4*)(in + (size_t)(two ? r0 + 1 : r0) * FDIM);
  float4 acc0[8], acc1[8];
#pragma unroll
  for (int j = 0; j < 8; ++j) {
    acc0[j] = make_float4(0.f, 0.f, 0.f, 0.f);
    acc1[j] = make_float4(0.f, 0.f, 0.f, 0.f);
  }
  for (int k4 = 0; k4 < FDIM / 4; ++k4) {
    float4 xa = a4[k4];
    float4 xb = b4[k4];
#pragma unroll
    for (int kk = 0; kk < 4; ++kk) {
      float av = (&xa.x)[kk];
      float bv = (&xb.x)[kk];
      const float4* wrow = (const float4*)(wl + (k4 * 4 + kk) * FDIM);
#pragma unroll
      for (int jv = 0; jv < 8; ++jv) {
        float4 w = wrow[lc + jv * 4];
        acc0[jv].x += av * w.x; acc0[jv].y += av * w.y;
        acc0[jv].z += av * w.z; acc0[jv].w += av * w.w;
        acc1[jv].x += bv * w.x; acc1[jv].y += bv * w.y;
        acc1[jv].z += bv * w.z; acc1[jv].w += bv * w.w;
      }
    }
  }
  float d0 = dinv[r0];
  float4* o0 = (float4*)(out + (size_t)r0 * FDIM);
#pragma unroll
  for (int jv = 0; jv < 8; ++jv) {
    float4 v = acc0[jv];
    v.x *= d0; v.y *= d0; v.z *= d0; v.w *= d0;
    o0[lc + jv * 4] = v;
  }
  if (two) {
    float d1 = dinv[r0 + 1];
    float4* o1 = (float4*)(out + (size_t)(r0 + 1) * FDIM);
#pragma unroll
    for (int jv = 0; jv < 8; ++jv) {
      float4 v = acc1[jv];
      v.x *= d1; v.y *= d1; v.z *= d1; v.w *= d1;
      o1[lc + jv * 4] = v;
    }
  }
}

// ---------------- aggregation: one wave per node ----------------
// h[v] = relu( dinv[v] * (s[v] + sum_{u->v} s[u]) + bias )
__global__ __launch_bounds__(256)
void k_aggregate(const float* __restrict__ s, const int* __restrict__ offs,
                 const int* __restrict__ cnt, const int* __restrict__ srcs,
                 const float* __restrict__ dinv, const float* __restrict__ bias,
                 float* __restrict__ h, int n) {
  int v = (int)(((size_t)blockIdx.x * blockDim.x + threadIdx.x) >> 6);
  if (v >= n) return;
  int lane = threadIdx.x & 63;
  const float2* s2 = (const float2*)s;
  float2 acc = s2[(size_t)v * 64 + lane];  // self contribution
  int beg = offs[v];
  int m = cnt[v];
  int u_next = (m > 0) ? srcs[beg] : 0;
  for (int it = 0; it < m; ++it) {
    int u = u_next;
    if (it + 1 < m) u_next = srcs[beg + it + 1];
    float2 tv = s2[(size_t)u * 64 + lane];
    acc.x += tv.x;
    acc.y += tv.y;
  }
  float d = dinv[v];
  float2 b = ((const float2*)bias)[lane];
  float rx = fmaxf(acc.x * d + b.x, 0.0f);
  float ry = fmaxf(acc.y * d + b.y, 0.0f);
  float2 r;
  r.x = rx;
  r.y = ry;
  ((float2*)h)[(size_t)v * 64 + lane] = r;
}

// ---------------- head: sigmoid(h @ Wl + bl), one wave per node ----------------
__global__ __launch_bounds__(256)
void k_final(const float* __restrict__ h, const float* __restrict__ Wl,
             const float* __restrict__ bl, float* __restrict__ out, int n) {
  int v = (int)(((size_t)blockIdx.x * blockDim.x + threadIdx.x) >> 6);
  if (v >= n) return;
  int lane = threadIdx.x & 63;
  const float2* h2 = (const float2*)(h + (size_t)v * FDIM);
  const float2* w2 = (const float2*)Wl;
  float2 hv = h2[lane];
  float2 wv = w2[lane];
  float p = hv.x * wv.x + hv.y * wv.y;
#pragma unroll
  for (int off = 32; off > 0; off >>= 1) p += __shfl_down(p, off, 64);
  if (lane == 0) {
    float z = p + bl[0];
    out[v] = 1.0f / (1.0f + expf(-z));
  }
}

// ---------------- launch ----------------

extern "C" void kernel_launch(void* const* d_in, const int* in_sizes, int n_in,
                              void* d_out, int out_size, void* d_ws, size_t ws_size,
                              hipStream_t stream) {
  const float* x  = (const float*)d_in[0];
  const int*   ei = (const int*)d_in[1];
  const float* W1 = (const float*)d_in[2];
  const float* b1 = (const float*)d_in[3];
  const float* W2 = (const float*)d_in[4];
  const float* b2 = (const float*)d_in[5];
  const float* Wl = (const float*)d_in[6];
  const float* bl = (const float*)d_in[7];
  float* out = (float*)d_out;

  int n  = in_sizes[0] / FDIM;   // 100000
  int nE = in_sizes[1] / 2;      // 3200000
  const int* row = ei;
  const int* col = ei + nE;

  // workspace carve (~117 MB)
  float* s    = (float*)d_ws;                 // n*128
  float* h    = s + (size_t)n * FDIM;         // n*128
  float* dinv = h + (size_t)n * FDIM;         // n
  int*   cnt  = (int*)(dinv + n);             // n
  int*   offs = cnt + n;                      // n
  int*   cur  = offs + n;                     // n
  int*   srcs = cur + n;                      // nE
  int*   bsums = srcs + nE;                   // nchunks

  hipMemsetAsync(cnt, 0, (size_t)n * sizeof(int), stream);
  k_histo<<<1024, 256, 0, stream>>>(col, cnt, nE);
  int nchunks = (n + 1023) >> 10;
  k_scan_chunks<<<nchunks, 256, 0, stream>>>(cnt, offs, bsums, n);
  k_scan_bsums<<<1, 256, 0, stream>>>(bsums, nchunks);
  k_finalize<<<(n + 255) / 256, 256, 0, stream>>>(offs, bsums, cur, dinv, cnt, n);
  k_scatter<<<1024, 256, 0, stream>>>(row, col, cur, srcs, nE);

  int gemm_grid = (n + 127) / 128;
  int wave_grid = (n + 3) / 4;  // 4 waves / 256-thread block
  k_gemm_scale<<<gemm_grid, 256, 0, stream>>>(x, W1, dinv, s, n);
  k_aggregate<<<wave_grid, 256, 0, stream>>>(s, offs, cnt, srcs, dinv, b1, h, n);
  k_gemm_scale<<<gemm_grid, 256, 0, stream>>>(h, W2, dinv, s, n);
  k_aggregate<<<wave_grid, 256, 0, stream>>>(s, offs, cnt, srcs, dinv, b2, h, n);
  k_final<<<wave_grid, 256, 0, stream>>>(h, Wl, bl, out, n);
}

// Round 2
// 810.515 us; speedup vs baseline: 1.4110x; 1.4110x over previous
//
#include <hip/hip_runtime.h>
#include <math.h>

#define FDIM 128
#define BKT_BITS 8                 // 256 nodes per bucket
#define BKT_W (1 << BKT_BITS)

// ---------------- CSR build: two-level binning ----------------

// coarse bucket histogram (LDS-staged, ~100K global atomics total)
__global__ __launch_bounds__(256)
void k_bhist(const int* __restrict__ col, int* __restrict__ gbcnt, int nE, int nb) {
  __shared__ int lds[512];
  for (int i = threadIdx.x; i < 512; i += 256) lds[i] = 0;
  __syncthreads();
  int stride = gridDim.x * blockDim.x;
  for (int e = blockIdx.x * blockDim.x + threadIdx.x; e < nE; e += stride)
    atomicAdd(&lds[col[e] >> BKT_BITS], 1);
  __syncthreads();
  for (int b = threadIdx.x; b < nb; b += 256) {
    int c = lds[b];
    if (c) atomicAdd(&gbcnt[b], c);
  }
}

// exclusive scan of bucket counts (nb <= 512), init cursors
__global__ __launch_bounds__(512)
void k_bscan(const int* __restrict__ gbcnt, int* __restrict__ gboff,
             int* __restrict__ gcur, int nb, int nE) {
  __shared__ int lds[512];
  int t = threadIdx.x;
  lds[t] = (t < nb) ? gbcnt[t] : 0;
  __syncthreads();
  for (int off = 1; off < 512; off <<= 1) {
    int x = (t >= off) ? lds[t - off] : 0;
    __syncthreads();
    lds[t] += x;
    __syncthreads();
  }
  if (t < nb) {
    int excl = (t == 0) ? 0 : lds[t - 1];
    gboff[t] = excl;
    gcur[t] = excl;
  }
  if (t == 0) gboff[nb] = nE;
}

// level-1 scatter: bucket-contiguous (row,col) pairs, ~256B runs per bucket
__global__ __launch_bounds__(256)
void k_bin(const int* __restrict__ row, const int* __restrict__ col,
           int* __restrict__ gcur, int2* __restrict__ pairs, int nE, int chunk, int nb) {
  __shared__ int bcnt[512];
  __shared__ int lcur[512];
  int e0 = blockIdx.x * chunk;
  int e1 = min(e0 + chunk, nE);
  for (int i = threadIdx.x; i < 512; i += 256) bcnt[i] = 0;
  __syncthreads();
  for (int e = e0 + threadIdx.x; e < e1; e += 256)
    atomicAdd(&bcnt[col[e] >> BKT_BITS], 1);
  __syncthreads();
  for (int b = threadIdx.x; b < nb; b += 256) {
    int c = bcnt[b];
    lcur[b] = c ? atomicAdd(&gcur[b], c) : 0;
  }
  __syncthreads();
  for (int e = e0 + threadIdx.x; e < e1; e += 256) {
    int c = col[e];
    int p = atomicAdd(&lcur[c >> BKT_BITS], 1);
    pairs[p] = make_int2(row[e], c);
  }
}

// fine pass: one block per bucket. Local count -> scan -> per-node
// cnt/offs/dinv + LDS-cursor scatter of rows into srcs (L2-local region).
__global__ __launch_bounds__(256)
void k_fine(const int2* __restrict__ pairs, const int* __restrict__ gboff,
            int* __restrict__ srcs, int* __restrict__ offs, int* __restrict__ cnt,
            float* __restrict__ dinv, int n) {
  __shared__ int lcnt[256];
  __shared__ int lcur[256];
  int b = blockIdx.x;
  int t = threadIdx.x;
  int ebase = gboff[b];
  int eend = gboff[b + 1];
  lcnt[t] = 0;
  __syncthreads();
  for (int e = ebase + t; e < eend; e += 256)
    atomicAdd(&lcnt[pairs[e].y & (BKT_W - 1)], 1);
  __syncthreads();
  int orig = lcnt[t];
  for (int off = 1; off < 256; off <<= 1) {
    int x = (t >= off) ? lcnt[t - off] : 0;
    __syncthreads();
    lcnt[t] += x;
    __syncthreads();
  }
  int excl = lcnt[t] - orig;
  int v = (b << BKT_BITS) + t;
  if (v < n) {
    offs[v] = ebase + excl;
    cnt[v] = orig;
    dinv[v] = rsqrtf((float)(orig + 1));  // +1 self loop
  }
  lcur[t] = ebase + excl;
  __syncthreads();
  for (int e = ebase + t; e < eend; e += 256) {
    int2 pr = pairs[e];
    int p = atomicAdd(&lcur[pr.y & (BKT_W - 1)], 1);
    srcs[p] = pr.x;
  }
}

// ---------------- GEMM [n,128] x [128,128], epilogue *dinv[row] ----------------
__global__ __launch_bounds__(256, 2)
void k_gemm_scale(const float* __restrict__ in, const float* __restrict__ W,
                  const float* __restrict__ dinv, float* __restrict__ out, int n) {
  __shared__ float wl[FDIM * FDIM];
  {
    const float4* W4 = (const float4*)W;
    float4* wl4 = (float4*)wl;
    for (int i = threadIdx.x; i < FDIM * FDIM / 4; i += 256) wl4[i] = W4[i];
  }
  __syncthreads();
  int t = threadIdx.x;
  int r0 = blockIdx.x * 128 + ((t >> 2) << 1);
  if (r0 >= n) return;
  int lc = t & 3;
  bool two = (r0 + 1 < n);
  const float4* a4 = (const float4*)(in + (size_t)r0 * FDIM);
  const float4* b4 = (const float4*)(in + (size_t)(two ? r0 + 1 : r0) * FDIM);
  float4 acc0[8], acc1[8];
#pragma unroll
  for (int j = 0; j < 8; ++j) {
    acc0[j] = make_float4(0.f, 0.f, 0.f, 0.f);
    acc1[j] = make_float4(0.f, 0.f, 0.f, 0.f);
  }
  for (int k4 = 0; k4 < FDIM / 4; ++k4) {
    float4 xa = a4[k4];
    float4 xb = b4[k4];
#pragma unroll
    for (int kk = 0; kk < 4; ++kk) {
      float av = (&xa.x)[kk];
      float bv = (&xb.x)[kk];
      const float4* wrow = (const float4*)(wl + (k4 * 4 + kk) * FDIM);
#pragma unroll
      for (int jv = 0; jv < 8; ++jv) {
        float4 w = wrow[lc + jv * 4];
        acc0[jv].x += av * w.x; acc0[jv].y += av * w.y;
        acc0[jv].z += av * w.z; acc0[jv].w += av * w.w;
        acc1[jv].x += bv * w.x; acc1[jv].y += bv * w.y;
        acc1[jv].z += bv * w.z; acc1[jv].w += bv * w.w;
      }
    }
  }
  float d0 = dinv[r0];
  float4* o0 = (float4*)(out + (size_t)r0 * FDIM);
#pragma unroll
  for (int jv = 0; jv < 8; ++jv) {
    float4 v = acc0[jv];
    v.x *= d0; v.y *= d0; v.z *= d0; v.w *= d0;
    o0[lc + jv * 4] = v;
  }
  if (two) {
    float d1 = dinv[r0 + 1];
    float4* o1 = (float4*)(out + (size_t)(r0 + 1) * FDIM);
#pragma unroll
    for (int jv = 0; jv < 8; ++jv) {
      float4 v = acc1[jv];
      v.x *= d1; v.y *= d1; v.z *= d1; v.w *= d1;
      o1[lc + jv * 4] = v;
    }
  }
}

// ---------------- aggregation: one wave per node ----------------
// h[v] = relu( dinv[v] * (s[v] + sum_{u->v} s[u]) + bias )
__global__ __launch_bounds__(256)
void k_aggregate(const float* __restrict__ s, const int* __restrict__ offs,
                 const int* __restrict__ cnt, const int* __restrict__ srcs,
                 const float* __restrict__ dinv, const float* __restrict__ bias,
                 float* __restrict__ h, int n) {
  int v = (int)(((size_t)blockIdx.x * blockDim.x + threadIdx.x) >> 6);
  if (v >= n) return;
  int lane = threadIdx.x & 63;
  const float2* s2 = (const float2*)s;
  float2 acc = s2[(size_t)v * 64 + lane];  // self contribution
  int beg = offs[v];
  int m = cnt[v];
  for (int base = 0; base < m; base += 64) {
    int take = m - base;
    if (take > 64) take = 64;
    int idx = (lane < take) ? srcs[beg + base + lane] : 0;
    int it = 0;
    for (; it + 3 < take; it += 4) {
      int u0 = __shfl(idx, it, 64);
      int u1 = __shfl(idx, it + 1, 64);
      int u2 = __shfl(idx, it + 2, 64);
      int u3 = __shfl(idx, it + 3, 64);
      float2 t0 = s2[(size_t)u0 * 64 + lane];
      float2 t1 = s2[(size_t)u1 * 64 + lane];
      float2 t2 = s2[(size_t)u2 * 64 + lane];
      float2 t3 = s2[(size_t)u3 * 64 + lane];
      acc.x += (t0.x + t1.x) + (t2.x + t3.x);
      acc.y += (t0.y + t1.y) + (t2.y + t3.y);
    }
    for (; it < take; ++it) {
      int u = __shfl(idx, it, 64);
      float2 tv = s2[(size_t)u * 64 + lane];
      acc.x += tv.x;
      acc.y += tv.y;
    }
  }
  float d = dinv[v];
  float2 b = ((const float2*)bias)[lane];
  float2 r;
  r.x = fmaxf(acc.x * d + b.x, 0.0f);
  r.y = fmaxf(acc.y * d + b.y, 0.0f);
  ((float2*)h)[(size_t)v * 64 + lane] = r;
}

// ---------------- head: sigmoid(h @ Wl + bl), one wave per node ----------------
__global__ __launch_bounds__(256)
void k_final(const float* __restrict__ h, const float* __restrict__ Wl,
             const float* __restrict__ bl, float* __restrict__ out, int n) {
  int v = (int)(((size_t)blockIdx.x * blockDim.x + threadIdx.x) >> 6);
  if (v >= n) return;
  int lane = threadIdx.x & 63;
  const float2* h2 = (const float2*)(h + (size_t)v * FDIM);
  const float2* w2 = (const float2*)Wl;
  float2 hv = h2[lane];
  float2 wv = w2[lane];
  float p = hv.x * wv.x + hv.y * wv.y;
#pragma unroll
  for (int off = 32; off > 0; off >>= 1) p += __shfl_down(p, off, 64);
  if (lane == 0) {
    float z = p + bl[0];
    out[v] = 1.0f / (1.0f + expf(-z));
  }
}

// ---------------- launch ----------------

extern "C" void kernel_launch(void* const* d_in, const int* in_sizes, int n_in,
                              void* d_out, int out_size, void* d_ws, size_t ws_size,
                              hipStream_t stream) {
  const float* x  = (const float*)d_in[0];
  const int*   ei = (const int*)d_in[1];
  const float* W1 = (const float*)d_in[2];
  const float* b1 = (const float*)d_in[3];
  const float* W2 = (const float*)d_in[4];
  const float* b2 = (const float*)d_in[5];
  const float* Wl = (const float*)d_in[6];
  const float* bl = (const float*)d_in[7];
  float* out = (float*)d_out;

  int n  = in_sizes[0] / FDIM;   // 100000
  int nE = in_sizes[1] / 2;      // 3200000
  const int* row = ei;
  const int* col = ei + nE;
  int nb = (n + BKT_W - 1) >> BKT_BITS;   // 391

  // workspace carve (~118 MB); pairs aliases h (h first written after CSR)
  float* s     = (float*)d_ws;                // n*128
  float* h     = s + (size_t)n * FDIM;        // n*128
  float* dinv  = h + (size_t)n * FDIM;        // n
  int*   cnt   = (int*)(dinv + n);            // n
  int*   offs  = cnt + n;                     // n
  int*   srcs  = offs + n;                    // nE
  int*   gbcnt = srcs + nE;                   // nb
  int*   gboff = gbcnt + nb;                  // nb+1
  int*   gcur  = gboff + nb + 1;              // nb
  int2*  pairs = (int2*)h;                    // nE (aliased)

  hipMemsetAsync(gbcnt, 0, (size_t)nb * sizeof(int), stream);
  k_bhist<<<256, 256, 0, stream>>>(col, gbcnt, nE, nb);
  k_bscan<<<1, 512, 0, stream>>>(gbcnt, gboff, gcur, nb, nE);
  int chunk = (nE + 255) / 256;
  k_bin<<<256, 256, 0, stream>>>(row, col, gcur, pairs, nE, chunk, nb);
  k_fine<<<nb, 256, 0, stream>>>(pairs, gboff, srcs, offs, cnt, dinv, n);

  int gemm_grid = (n + 127) / 128;
  int wave_grid = (n + 3) / 4;  // 4 waves / 256-thread block
  k_gemm_scale<<<gemm_grid, 256, 0, stream>>>(x, W1, dinv, s, n);
  k_aggregate<<<wave_grid, 256, 0, stream>>>(s, offs, cnt, srcs, dinv, b1, h, n);
  k_gemm_scale<<<gemm_grid, 256, 0, stream>>>(h, W2, dinv, s, n);
  k_aggregate<<<wave_grid, 256, 0, stream>>>(s, offs, cnt, srcs, dinv, b2, h, n);
  k_final<<<wave_grid, 256, 0, stream>>>(h, Wl, bl, out, n);
}

// Round 4
// 612.995 us; speedup vs baseline: 1.8657x; 1.3222x over previous
//
#include <hip/hip_runtime.h>
#include <math.h>

#define FDIM 128
#define BKT_BITS 8                 // 256 nodes per bucket
#define BKT_W (1 << BKT_BITS)

__device__ inline unsigned int pack_bf16x2(float a, float b) {
  unsigned int ua = __float_as_uint(a);
  unsigned int ub = __float_as_uint(b);
  ua = (ua + 0x7fffu + ((ua >> 16) & 1u)) >> 16;   // RNE
  ub = (ub + 0x7fffu + ((ub >> 16) & 1u)) >> 16;
  return ua | (ub << 16);
}

// ---------------- CSR build: two-level binning ----------------

__global__ __launch_bounds__(256)
void k_bhist(const int* __restrict__ col, int* __restrict__ gbcnt, int nE, int nb) {
  __shared__ int lds[512];
  for (int i = threadIdx.x; i < 512; i += 256) lds[i] = 0;
  __syncthreads();
  int stride = gridDim.x * blockDim.x;
  for (int e = blockIdx.x * blockDim.x + threadIdx.x; e < nE; e += stride)
    atomicAdd(&lds[col[e] >> BKT_BITS], 1);
  __syncthreads();
  for (int b = threadIdx.x; b < nb; b += 256) {
    int c = lds[b];
    if (c) atomicAdd(&gbcnt[b], c);
  }
}

__global__ __launch_bounds__(512)
void k_bscan(const int* __restrict__ gbcnt, int* __restrict__ gboff,
             int* __restrict__ gcur, int nb, int nE) {
  __shared__ int lds[512];
  int t = threadIdx.x;
  lds[t] = (t < nb) ? gbcnt[t] : 0;
  __syncthreads();
  for (int off = 1; off < 512; off <<= 1) {
    int x = (t >= off) ? lds[t - off] : 0;
    __syncthreads();
    lds[t] += x;
    __syncthreads();
  }
  if (t < nb) {
    int excl = (t == 0) ? 0 : lds[t - 1];
    gboff[t] = excl;
    gcur[t] = excl;
  }
  if (t == 0) gboff[nb] = nE;
}

__global__ __launch_bounds__(256)
void k_bin(const int* __restrict__ row, const int* __restrict__ col,
           int* __restrict__ gcur, int2* __restrict__ pairs, int nE, int chunk, int nb) {
  __shared__ int bcnt[512];
  __shared__ int lcur[512];
  int e0 = blockIdx.x * chunk;
  int e1 = min(e0 + chunk, nE);
  for (int i = threadIdx.x; i < 512; i += 256) bcnt[i] = 0;
  __syncthreads();
  for (int e = e0 + threadIdx.x; e < e1; e += 256)
    atomicAdd(&bcnt[col[e] >> BKT_BITS], 1);
  __syncthreads();
  for (int b = threadIdx.x; b < nb; b += 256) {
    int c = bcnt[b];
    lcur[b] = c ? atomicAdd(&gcur[b], c) : 0;
  }
  __syncthreads();
  for (int e = e0 + threadIdx.x; e < e1; e += 256) {
    int c = col[e];
    int p = atomicAdd(&lcur[c >> BKT_BITS], 1);
    pairs[p] = make_int2(row[e], c);
  }
}

__global__ __launch_bounds__(256)
void k_fine(const int2* __restrict__ pairs, const int* __restrict__ gboff,
            int* __restrict__ srcs, int* __restrict__ offs, int* __restrict__ cnt,
            float* __restrict__ dinv, int n) {
  __shared__ int lcnt[256];
  __shared__ int lcur[256];
  int b = blockIdx.x;
  int t = threadIdx.x;
  int ebase = gboff[b];
  int eend = gboff[b + 1];
  lcnt[t] = 0;
  __syncthreads();
  for (int e = ebase + t; e < eend; e += 256)
    atomicAdd(&lcnt[pairs[e].y & (BKT_W - 1)], 1);
  __syncthreads();
  int orig = lcnt[t];
  for (int off = 1; off < 256; off <<= 1) {
    int x = (t >= off) ? lcnt[t - off] : 0;
    __syncthreads();
    lcnt[t] += x;
    __syncthreads();
  }
  int excl = lcnt[t] - orig;
  int v = (b << BKT_BITS) + t;
  if (v < n) {
    offs[v] = ebase + excl;
    cnt[v] = orig;
    dinv[v] = rsqrtf((float)(orig + 1));  // +1 self loop
  }
  lcur[t] = ebase + excl;
  __syncthreads();
  for (int e = ebase + t; e < eend; e += 256) {
    int2 pr = pairs[e];
    int p = atomicAdd(&lcur[pr.y & (BKT_W - 1)], 1);
    srcs[p] = pr.x;
  }
}

// ------- GEMM [n,128] x [128,128], epilogue *dinv[row], bf16 output -------
__global__ __launch_bounds__(256, 2)
void k_gemm_scale(const float* __restrict__ in, const float* __restrict__ W,
                  const float* __restrict__ dinv, unsigned int* __restrict__ out,
                  int n) {
  __shared__ float wl[FDIM * FDIM];
  {
    const float4* W4 = (const float4*)W;
    float4* wl4 = (float4*)wl;
    for (int i = threadIdx.x; i < FDIM * FDIM / 4; i += 256) wl4[i] = W4[i];
  }
  __syncthreads();
  int t = threadIdx.x;
  int r0 = blockIdx.x * 128 + ((t >> 2) << 1);
  if (r0 >= n) return;
  int lc = t & 3;
  bool two = (r0 + 1 < n);
  const float4* a4 = (const float4*)(in + (size_t)r0 * FDIM);
  const float4* b4 = (const float4*)(in + (size_t)(two ? r0 + 1 : r0) * FDIM);
  float4 acc0[8], acc1[8];
#pragma unroll
  for (int j = 0; j < 8; ++j) {
    acc0[j] = make_float4(0.f, 0.f, 0.f, 0.f);
    acc1[j] = make_float4(0.f, 0.f, 0.f, 0.f);
  }
  for (int k4 = 0; k4 < FDIM / 4; ++k4) {
    float4 xa = a4[k4];
    float4 xb = b4[k4];
#pragma unroll
    for (int kk = 0; kk < 4; ++kk) {
      float av = (&xa.x)[kk];
      float bv = (&xb.x)[kk];
      const float4* wrow = (const float4*)(wl + (k4 * 4 + kk) * FDIM);
#pragma unroll
      for (int jv = 0; jv < 8; ++jv) {
        float4 w = wrow[lc + jv * 4];
        acc0[jv].x += av * w.x; acc0[jv].y += av * w.y;
        acc0[jv].z += av * w.z; acc0[jv].w += av * w.w;
        acc1[jv].x += bv * w.x; acc1[jv].y += bv * w.y;
        acc1[jv].z += bv * w.z; acc1[jv].w += bv * w.w;
      }
    }
  }
  float d0 = dinv[r0];
  uint2* o0 = (uint2*)(out + (size_t)r0 * (FDIM / 2));
#pragma unroll
  for (int jv = 0; jv < 8; ++jv) {
    float4 v = acc0[jv];
    uint2 pk;
    pk.x = pack_bf16x2(v.x * d0, v.y * d0);
    pk.y = pack_bf16x2(v.z * d0, v.w * d0);
    o0[lc + jv * 4] = pk;
  }
  if (two) {
    float d1 = dinv[r0 + 1];
    uint2* o1 = (uint2*)(out + (size_t)(r0 + 1) * (FDIM / 2));
#pragma unroll
    for (int jv = 0; jv < 8; ++jv) {
      float4 v = acc1[jv];
      uint2 pk;
      pk.x = pack_bf16x2(v.x * d1, v.y * d1);
      pk.y = pack_bf16x2(v.z * d1, v.w * d1);
      o1[lc + jv * 4] = pk;
    }
  }
}

// ---------------- aggregation: one wave per node, bf16 gather ----------------
// h[v] = relu( dinv[v] * (s[v] + sum_{u->v} s[u]) + bias )
__global__ __launch_bounds__(256)
void k_aggregate(const unsigned int* __restrict__ sb, const int* __restrict__ offs,
                 const int* __restrict__ cnt, const int* __restrict__ srcs,
                 const float* __restrict__ dinv, const float* __restrict__ bias,
                 float* __restrict__ h, int n) {
  int v = (int)(((size_t)blockIdx.x * blockDim.x + threadIdx.x) >> 6);
  if (v >= n) return;
  int lane = threadIdx.x & 63;
  float2 acc;
  {
    unsigned int p = sb[(size_t)v * 64 + lane];  // self contribution
    acc.x = __uint_as_float(p << 16);
    acc.y = __uint_as_float(p & 0xffff0000u);
  }
  int beg = offs[v];
  int m = cnt[v];
  for (int base = 0; base < m; base += 64) {
    int take = m - base;
    if (take > 64) take = 64;
    int idx = (lane < take) ? srcs[beg + base + lane] : 0;
    int it = 0;
    for (; it + 3 < take; it += 4) {
      int u0 = __shfl(idx, it, 64);
      int u1 = __shfl(idx, it + 1, 64);
      int u2 = __shfl(idx, it + 2, 64);
      int u3 = __shfl(idx, it + 3, 64);
      unsigned int p0 = sb[(size_t)u0 * 64 + lane];
      unsigned int p1 = sb[(size_t)u1 * 64 + lane];
      unsigned int p2 = sb[(size_t)u2 * 64 + lane];
      unsigned int p3 = sb[(size_t)u3 * 64 + lane];
      acc.x += (__uint_as_float(p0 << 16) + __uint_as_float(p1 << 16)) +
               (__uint_as_float(p2 << 16) + __uint_as_float(p3 << 16));
      acc.y += (__uint_as_float(p0 & 0xffff0000u) + __uint_as_float(p1 & 0xffff0000u)) +
               (__uint_as_float(p2 & 0xffff0000u) + __uint_as_float(p3 & 0xffff0000u));
    }
    for (; it < take; ++it) {
      int u = __shfl(idx, it, 64);
      unsigned int p = sb[(size_t)u * 64 + lane];
      acc.x += __uint_as_float(p << 16);
      acc.y += __uint_as_float(p & 0xffff0000u);
    }
  }
  float d = dinv[v];
  float2 b = ((const float2*)bias)[lane];
  float2 r;
  r.x = fmaxf(acc.x * d + b.x, 0.0f);
  r.y = fmaxf(acc.y * d + b.y, 0.0f);
  ((float2*)h)[(size_t)v * 64 + lane] = r;
}

// ---------------- head: sigmoid(h @ Wl + bl), one wave per node ----------------
__global__ __launch_bounds__(256)
void k_final(const float* __restrict__ h, const float* __restrict__ Wl,
             const float* __restrict__ bl, float* __restrict__ out, int n) {
  int v = (int)(((size_t)blockIdx.x * blockDim.x + threadIdx.x) >> 6);
  if (v >= n) return;
  int lane = threadIdx.x & 63;
  const float2* h2 = (const float2*)(h + (size_t)v * FDIM);
  const float2* w2 = (const float2*)Wl;
  float2 hv = h2[lane];
  float2 wv = w2[lane];
  float p = hv.x * wv.x + hv.y * wv.y;
#pragma unroll
  for (int off = 32; off > 0; off >>= 1) p += __shfl_down(p, off, 64);
  if (lane == 0) {
    float z = p + bl[0];
    out[v] = 1.0f / (1.0f + expf(-z));
  }
}

// ---------------- launch ----------------

extern "C" void kernel_launch(void* const* d_in, const int* in_sizes, int n_in,
                              void* d_out, int out_size, void* d_ws, size_t ws_size,
                              hipStream_t stream) {
  const float* x  = (const float*)d_in[0];
  const int*   ei = (const int*)d_in[1];
  const float* W1 = (const float*)d_in[2];
  const float* b1 = (const float*)d_in[3];
  const float* W2 = (const float*)d_in[4];
  const float* b2 = (const float*)d_in[5];
  const float* Wl = (const float*)d_in[6];
  const float* bl = (const float*)d_in[7];
  float* out = (float*)d_out;

  int n  = in_sizes[0] / FDIM;   // 100000
  int nE = in_sizes[1] / 2;      // 3200000
  const int* row = ei;
  const int* col = ei + nE;
  int nb = (n + BKT_W - 1) >> BKT_BITS;   // 391

  // workspace carve; pairs aliases h (h first written after CSR consumed)
  unsigned int* s = (unsigned int*)d_ws;         // n*64 dwords (bf16 x2) = 25.6 MB
  float* h     = (float*)(s + (size_t)n * 64);   // n*128 fp32
  float* dinv  = h + (size_t)n * FDIM;           // n
  int*   cnt   = (int*)(dinv + n);               // n
  int*   offs  = cnt + n;                        // n
  int*   srcs  = offs + n;                       // nE
  int*   gbcnt = srcs + nE;                      // nb
  int*   gboff = gbcnt + nb;                     // nb+1
  int*   gcur  = gboff + nb + 1;                 // nb
  int2*  pairs = (int2*)h;                       // nE (aliased)

  hipMemsetAsync(gbcnt, 0, (size_t)nb * sizeof(int), stream);
  k_bhist<<<256, 256, 0, stream>>>(col, gbcnt, nE, nb);
  k_bscan<<<1, 512, 0, stream>>>(gbcnt, gboff, gcur, nb, nE);
  int chunk = (nE + 255) / 256;
  k_bin<<<256, 256, 0, stream>>>(row, col, gcur, pairs, nE, chunk, nb);
  k_fine<<<nb, 256, 0, stream>>>(pairs, gboff, srcs, offs, cnt, dinv, n);

  int gemm_grid = (n + 127) / 128;
  int wave_grid = (n + 3) / 4;  // 4 waves / 256-thread block
  k_gemm_scale<<<gemm_grid, 256, 0, stream>>>(x, W1, dinv, s, n);
  k_aggregate<<<wave_grid, 256, 0, stream>>>(s, offs, cnt, srcs, dinv, b1, h, n);
  k_gemm_scale<<<gemm_grid, 256, 0, stream>>>(h, W2, dinv, s, n);
  k_aggregate<<<wave_grid, 256, 0, stream>>>(s, offs, cnt, srcs, dinv, b2, h, n);
  k_final<<<wave_grid, 256, 0, stream>>>(h, Wl, bl, out, n);
}

// Round 5
// 537.463 us; speedup vs baseline: 2.1279x; 1.1405x over previous
//
#include <hip/hip_runtime.h>
#include <math.h>

#define FDIM 128
#define BKT_BITS 8                 // 256 nodes per bucket
#define BKT_W (1 << BKT_BITS)
#define BIN_CHUNK 12544            // max edges per k_bin block (50 KB LDS)

__device__ inline unsigned int pack_bf16x2(float a, float b) {
  unsigned int ua = __float_as_uint(a);
  unsigned int ub = __float_as_uint(b);
  ua = (ua + 0x7fffu + ((ua >> 16) & 1u)) >> 16;   // RNE
  ub = (ub + 0x7fffu + ((ub >> 16) & 1u)) >> 16;
  return ua | (ub << 16);
}

// ---------------- CSR build: two-level binning ----------------

__global__ __launch_bounds__(256)
void k_bhist(const int* __restrict__ col, int* __restrict__ gbcnt, int nE, int nb) {
  __shared__ int lds[512];
  for (int i = threadIdx.x; i < 512; i += 256) lds[i] = 0;
  __syncthreads();
  int stride = gridDim.x * blockDim.x;
  for (int e = blockIdx.x * blockDim.x + threadIdx.x; e < nE; e += stride)
    atomicAdd(&lds[col[e] >> BKT_BITS], 1);
  __syncthreads();
  for (int b = threadIdx.x; b < nb; b += 256) {
    int c = lds[b];
    if (c) atomicAdd(&gbcnt[b], c);
  }
}

__global__ __launch_bounds__(512)
void k_bscan(const int* __restrict__ gbcnt, int* __restrict__ gboff,
             int* __restrict__ gcur, int nb, int nE) {
  __shared__ int lds[512];
  int t = threadIdx.x;
  lds[t] = (t < nb) ? gbcnt[t] : 0;
  __syncthreads();
  for (int off = 1; off < 512; off <<= 1) {
    int x = (t >= off) ? lds[t - off] : 0;
    __syncthreads();
    lds[t] += x;
    __syncthreads();
  }
  if (t < nb) {
    int excl = (t == 0) ? 0 : lds[t - 1];
    gboff[t] = excl;
    gcur[t] = excl;
  }
  if (t == 0) gboff[nb] = nE;
}

// level-1 scatter: packed (row | col_low<<24), bucket-contiguous.
// col chunk staged in LDS so global col is read exactly once.
__global__ __launch_bounds__(256)
void k_bin(const int* __restrict__ row, const int* __restrict__ col,
           int* __restrict__ gcur, int* __restrict__ pairs, int nE, int chunk, int nb) {
  __shared__ int bcnt[512];
  __shared__ int lcur[512];
  __shared__ int ecol[BIN_CHUNK];
  int e0 = blockIdx.x * chunk;
  int e1 = min(e0 + chunk, nE);
  int m = e1 - e0;
  for (int i = threadIdx.x; i < 512; i += 256) bcnt[i] = 0;
  for (int i = threadIdx.x; i < m; i += 256) ecol[i] = col[e0 + i];
  __syncthreads();
  for (int i = threadIdx.x; i < m; i += 256)
    atomicAdd(&bcnt[((unsigned)ecol[i]) >> BKT_BITS], 1);
  __syncthreads();
  for (int b = threadIdx.x; b < nb; b += 256) {
    int c = bcnt[b];
    lcur[b] = c ? atomicAdd(&gcur[b], c) : 0;
  }
  __syncthreads();
  for (int i = threadIdx.x; i < m; i += 256) {
    int c = ecol[i];
    int r = row[e0 + i];
    int p = atomicAdd(&lcur[((unsigned)c) >> BKT_BITS], 1);
    pairs[p] = r | ((c & (BKT_W - 1)) << 24);
  }
}

// fine pass: one block per bucket. cnt/offs/dinv + LDS-cursor scatter of rows.
__global__ __launch_bounds__(256)
void k_fine(const int* __restrict__ pairs, const int* __restrict__ gboff,
            int* __restrict__ srcs, int* __restrict__ offs, int* __restrict__ cnt,
            float* __restrict__ dinv, int n) {
  __shared__ int lcnt[256];
  __shared__ int lcur[256];
  int b = blockIdx.x;
  int t = threadIdx.x;
  int ebase = gboff[b];
  int eend = gboff[b + 1];
  lcnt[t] = 0;
  __syncthreads();
  for (int e = ebase + t; e < eend; e += 256)
    atomicAdd(&lcnt[((unsigned)pairs[e]) >> 24], 1);
  __syncthreads();
  int orig = lcnt[t];
  for (int off = 1; off < 256; off <<= 1) {
    int x = (t >= off) ? lcnt[t - off] : 0;
    __syncthreads();
    lcnt[t] += x;
    __syncthreads();
  }
  int excl = lcnt[t] - orig;
  int v = (b << BKT_BITS) + t;
  if (v < n) {
    offs[v] = ebase + excl;
    cnt[v] = orig;
    dinv[v] = rsqrtf((float)(orig + 1));  // +1 self loop
  }
  lcur[t] = ebase + excl;
  __syncthreads();
  for (int e = ebase + t; e < eend; e += 256) {
    int pr = pairs[e];
    int p = atomicAdd(&lcur[((unsigned)pr) >> 24], 1);
    srcs[p] = pr & 0x00FFFFFF;
  }
}

// ------- GEMM [n,128] x [128,128] fp32-in, epilogue *dinv[row], bf16 out -------
__global__ __launch_bounds__(256, 2)
void k_gemm_scale(const float* __restrict__ in, const float* __restrict__ W,
                  const float* __restrict__ dinv, unsigned int* __restrict__ out,
                  int n) {
  __shared__ float wl[FDIM * FDIM];
  {
    const float4* W4 = (const float4*)W;
    float4* wl4 = (float4*)wl;
    for (int i = threadIdx.x; i < FDIM * FDIM / 4; i += 256) wl4[i] = W4[i];
  }
  __syncthreads();
  int t = threadIdx.x;
  int r0 = blockIdx.x * 128 + ((t >> 2) << 1);
  if (r0 >= n) return;
  int lc = t & 3;
  bool two = (r0 + 1 < n);
  const float4* a4 = (const float4*)(in + (size_t)r0 * FDIM);
  const float4* b4 = (const float4*)(in + (size_t)(two ? r0 + 1 : r0) * FDIM);
  float4 acc0[8], acc1[8];
#pragma unroll
  for (int j = 0; j < 8; ++j) {
    acc0[j] = make_float4(0.f, 0.f, 0.f, 0.f);
    acc1[j] = make_float4(0.f, 0.f, 0.f, 0.f);
  }
  for (int k4 = 0; k4 < FDIM / 4; ++k4) {
    float4 xa = a4[k4];
    float4 xb = b4[k4];
#pragma unroll
    for (int kk = 0; kk < 4; ++kk) {
      float av = (&xa.x)[kk];
      float bv = (&xb.x)[kk];
      const float4* wrow = (const float4*)(wl + (k4 * 4 + kk) * FDIM);
#pragma unroll
      for (int jv = 0; jv < 8; ++jv) {
        float4 w = wrow[lc + jv * 4];
        acc0[jv].x += av * w.x; acc0[jv].y += av * w.y;
        acc0[jv].z += av * w.z; acc0[jv].w += av * w.w;
        acc1[jv].x += bv * w.x; acc1[jv].y += bv * w.y;
        acc1[jv].z += bv * w.z; acc1[jv].w += bv * w.w;
      }
    }
  }
  float d0 = dinv[r0];
  uint2* o0 = (uint2*)(out + (size_t)r0 * (FDIM / 2));
#pragma unroll
  for (int jv = 0; jv < 8; ++jv) {
    float4 v = acc0[jv];
    uint2 pk;
    pk.x = pack_bf16x2(v.x * d0, v.y * d0);
    pk.y = pack_bf16x2(v.z * d0, v.w * d0);
    o0[lc + jv * 4] = pk;
  }
  if (two) {
    float d1 = dinv[r0 + 1];
    uint2* o1 = (uint2*)(out + (size_t)(r0 + 1) * (FDIM / 2));
#pragma unroll
    for (int jv = 0; jv < 8; ++jv) {
      float4 v = acc1[jv];
      uint2 pk;
      pk.x = pack_bf16x2(v.x * d1, v.y * d1);
      pk.y = pack_bf16x2(v.z * d1, v.w * d1);
      o1[lc + jv * 4] = pk;
    }
  }
}

// ------- GEMM bf16-in (layer 2): [n,128]bf16 x [128,128], *dinv, bf16 out -------
__global__ __launch_bounds__(256, 2)
void k_gemm_scale_b(const unsigned int* __restrict__ in, const float* __restrict__ W,
                    const float* __restrict__ dinv, unsigned int* __restrict__ out,
                    int n) {
  __shared__ float wl[FDIM * FDIM];
  {
    const float4* W4 = (const float4*)W;
    float4* wl4 = (float4*)wl;
    for (int i = threadIdx.x; i < FDIM * FDIM / 4; i += 256) wl4[i] = W4[i];
  }
  __syncthreads();
  int t = threadIdx.x;
  int r0 = blockIdx.x * 128 + ((t >> 2) << 1);
  if (r0 >= n) return;
  int lc = t & 3;
  bool two = (r0 + 1 < n);
  const uint2* a4 = (const uint2*)(in + (size_t)r0 * (FDIM / 2));
  const uint2* b4 = (const uint2*)(in + (size_t)(two ? r0 + 1 : r0) * (FDIM / 2));
  float4 acc0[8], acc1[8];
#pragma unroll
  for (int j = 0; j < 8; ++j) {
    acc0[j] = make_float4(0.f, 0.f, 0.f, 0.f);
    acc1[j] = make_float4(0.f, 0.f, 0.f, 0.f);
  }
  for (int k4 = 0; k4 < FDIM / 4; ++k4) {
    uint2 pa = a4[k4];
    uint2 pb = b4[k4];
    float xa[4], xb[4];
    xa[0] = __uint_as_float(pa.x << 16); xa[1] = __uint_as_float(pa.x & 0xffff0000u);
    xa[2] = __uint_as_float(pa.y << 16); xa[3] = __uint_as_float(pa.y & 0xffff0000u);
    xb[0] = __uint_as_float(pb.x << 16); xb[1] = __uint_as_float(pb.x & 0xffff0000u);
    xb[2] = __uint_as_float(pb.y << 16); xb[3] = __uint_as_float(pb.y & 0xffff0000u);
#pragma unroll
    for (int kk = 0; kk < 4; ++kk) {
      float av = xa[kk];
      float bv = xb[kk];
      const float4* wrow = (const float4*)(wl + (k4 * 4 + kk) * FDIM);
#pragma unroll
      for (int jv = 0; jv < 8; ++jv) {
        float4 w = wrow[lc + jv * 4];
        acc0[jv].x += av * w.x; acc0[jv].y += av * w.y;
        acc0[jv].z += av * w.z; acc0[jv].w += av * w.w;
        acc1[jv].x += bv * w.x; acc1[jv].y += bv * w.y;
        acc1[jv].z += bv * w.z; acc1[jv].w += bv * w.w;
      }
    }
  }
  float d0 = dinv[r0];
  uint2* o0 = (uint2*)(out + (size_t)r0 * (FDIM / 2));
#pragma unroll
  for (int jv = 0; jv < 8; ++jv) {
    float4 v = acc0[jv];
    uint2 pk;
    pk.x = pack_bf16x2(v.x * d0, v.y * d0);
    pk.y = pack_bf16x2(v.z * d0, v.w * d0);
    o0[lc + jv * 4] = pk;
  }
  if (two) {
    float d1 = dinv[r0 + 1];
    uint2* o1 = (uint2*)(out + (size_t)(r0 + 1) * (FDIM / 2));
#pragma unroll
    for (int jv = 0; jv < 8; ++jv) {
      float4 v = acc1[jv];
      uint2 pk;
      pk.x = pack_bf16x2(v.x * d1, v.y * d1);
      pk.y = pack_bf16x2(v.z * d1, v.w * d1);
      o1[lc + jv * 4] = pk;
    }
  }
}

// ---------------- gather-accumulate core (one wave per node) ----------------
__device__ inline float2 agg_core(const unsigned int* __restrict__ sb,
                                  const int* __restrict__ offs,
                                  const int* __restrict__ cnt,
                                  const int* __restrict__ srcs,
                                  int v, int lane) {
  float2 acc;
  {
    unsigned int p = sb[(size_t)v * 64 + lane];  // self contribution
    acc.x = __uint_as_float(p << 16);
    acc.y = __uint_as_float(p & 0xffff0000u);
  }
  int beg = offs[v];
  int m = cnt[v];
  for (int base = 0; base < m; base += 64) {
    int take = m - base;
    if (take > 64) take = 64;
    int idx = (lane < take) ? srcs[beg + base + lane] : 0;
    int it = 0;
    for (; it + 7 < take; it += 8) {
      int u0 = __shfl(idx, it, 64);
      int u1 = __shfl(idx, it + 1, 64);
      int u2 = __shfl(idx, it + 2, 64);
      int u3 = __shfl(idx, it + 3, 64);
      int u4 = __shfl(idx, it + 4, 64);
      int u5 = __shfl(idx, it + 5, 64);
      int u6 = __shfl(idx, it + 6, 64);
      int u7 = __shfl(idx, it + 7, 64);
      unsigned int p0 = sb[(size_t)u0 * 64 + lane];
      unsigned int p1 = sb[(size_t)u1 * 64 + lane];
      unsigned int p2 = sb[(size_t)u2 * 64 + lane];
      unsigned int p3 = sb[(size_t)u3 * 64 + lane];
      unsigned int p4 = sb[(size_t)u4 * 64 + lane];
      unsigned int p5 = sb[(size_t)u5 * 64 + lane];
      unsigned int p6 = sb[(size_t)u6 * 64 + lane];
      unsigned int p7 = sb[(size_t)u7 * 64 + lane];
      acc.x += ((__uint_as_float(p0 << 16) + __uint_as_float(p1 << 16)) +
                (__uint_as_float(p2 << 16) + __uint_as_float(p3 << 16))) +
               ((__uint_as_float(p4 << 16) + __uint_as_float(p5 << 16)) +
                (__uint_as_float(p6 << 16) + __uint_as_float(p7 << 16)));
      acc.y += ((__uint_as_float(p0 & 0xffff0000u) + __uint_as_float(p1 & 0xffff0000u)) +
                (__uint_as_float(p2 & 0xffff0000u) + __uint_as_float(p3 & 0xffff0000u))) +
               ((__uint_as_float(p4 & 0xffff0000u) + __uint_as_float(p5 & 0xffff0000u)) +
                (__uint_as_float(p6 & 0xffff0000u) + __uint_as_float(p7 & 0xffff0000u)));
    }
    for (; it < take; ++it) {
      int u = __shfl(idx, it, 64);
      unsigned int p = sb[(size_t)u * 64 + lane];
      acc.x += __uint_as_float(p << 16);
      acc.y += __uint_as_float(p & 0xffff0000u);
    }
  }
  return acc;
}

// layer-1 aggregate: h = relu(dinv*(...)+b), stored bf16
__global__ __launch_bounds__(256)
void k_agg_mid(const unsigned int* __restrict__ sb, const int* __restrict__ offs,
               const int* __restrict__ cnt, const int* __restrict__ srcs,
               const float* __restrict__ dinv, const float* __restrict__ bias,
               unsigned int* __restrict__ hb, int n) {
  int v = (int)(((size_t)blockIdx.x * blockDim.x + threadIdx.x) >> 6);
  if (v >= n) return;
  int lane = threadIdx.x & 63;
  float2 acc = agg_core(sb, offs, cnt, srcs, v, lane);
  float d = dinv[v];
  float2 b = ((const float2*)bias)[lane];
  float rx = fmaxf(acc.x * d + b.x, 0.0f);
  float ry = fmaxf(acc.y * d + b.y, 0.0f);
  hb[(size_t)v * 64 + lane] = pack_bf16x2(rx, ry);
}

// layer-2 aggregate fused with head: out = sigmoid(relu(...)@Wl + bl)
__global__ __launch_bounds__(256)
void k_agg_head(const unsigned int* __restrict__ sb, const int* __restrict__ offs,
                const int* __restrict__ cnt, const int* __restrict__ srcs,
                const float* __restrict__ dinv, const float* __restrict__ bias,
                const float* __restrict__ Wl, const float* __restrict__ bl,
                float* __restrict__ out, int n) {
  int v = (int)(((size_t)blockIdx.x * blockDim.x + threadIdx.x) >> 6);
  if (v >= n) return;
  int lane = threadIdx.x & 63;
  float2 acc = agg_core(sb, offs, cnt, srcs, v, lane);
  float d = dinv[v];
  float2 b = ((const float2*)bias)[lane];
  float rx = fmaxf(acc.x * d + b.x, 0.0f);
  float ry = fmaxf(acc.y * d + b.y, 0.0f);
  float2 wv = ((const float2*)Wl)[lane];
  float p = rx * wv.x + ry * wv.y;
#pragma unroll
  for (int off = 32; off > 0; off >>= 1) p += __shfl_down(p, off, 64);
  if (lane == 0) {
    float z = p + bl[0];
    out[v] = 1.0f / (1.0f + expf(-z));
  }
}

// ---------------- launch ----------------

extern "C" void kernel_launch(void* const* d_in, const int* in_sizes, int n_in,
                              void* d_out, int out_size, void* d_ws, size_t ws_size,
                              hipStream_t stream) {
  const float* x  = (const float*)d_in[0];
  const int*   ei = (const int*)d_in[1];
  const float* W1 = (const float*)d_in[2];
  const float* b1 = (const float*)d_in[3];
  const float* W2 = (const float*)d_in[4];
  const float* b2 = (const float*)d_in[5];
  const float* Wl = (const float*)d_in[6];
  const float* bl = (const float*)d_in[7];
  float* out = (float*)d_out;

  int n  = in_sizes[0] / FDIM;   // 100000
  int nE = in_sizes[1] / 2;      // 3200000
  const int* row = ei;
  const int* col = ei + nE;
  int nb = (n + BKT_W - 1) >> BKT_BITS;   // 391

  // workspace carve (~66 MB); pairs aliases hb (hb first written after k_fine)
  unsigned int* s  = (unsigned int*)d_ws;          // n*64 dwords (bf16x2)
  unsigned int* hb = s + (size_t)n * 64;           // n*64 dwords (bf16x2)
  float* dinv  = (float*)(hb + (size_t)n * 64);    // n
  int*   cnt   = (int*)(dinv + n);                 // n
  int*   offs  = cnt + n;                          // n
  int*   srcs  = offs + n;                         // nE
  int*   gbcnt = srcs + nE;                        // nb
  int*   gboff = gbcnt + nb;                       // nb+1
  int*   gcur  = gboff + nb + 1;                   // nb
  int*   pairs = (int*)hb;                         // nE packed (aliased)

  hipMemsetAsync(gbcnt, 0, (size_t)nb * sizeof(int), stream);
  k_bhist<<<256, 256, 0, stream>>>(col, gbcnt, nE, nb);
  k_bscan<<<1, 512, 0, stream>>>(gbcnt, gboff, gcur, nb, nE);
  int chunk = (nE + 255) / 256;   // 12500 <= BIN_CHUNK
  k_bin<<<256, 256, 0, stream>>>(row, col, gcur, pairs, nE, chunk, nb);
  k_fine<<<nb, 256, 0, stream>>>(pairs, gboff, srcs, offs, cnt, dinv, n);

  int gemm_grid = (n + 127) / 128;
  int wave_grid = (n + 3) / 4;  // 4 waves / 256-thread block
  k_gemm_scale<<<gemm_grid, 256, 0, stream>>>(x, W1, dinv, s, n);
  k_agg_mid<<<wave_grid, 256, 0, stream>>>(s, offs, cnt, srcs, dinv, b1, hb, n);
  k_gemm_scale_b<<<gemm_grid, 256, 0, stream>>>(hb, W2, dinv, s, n);
  k_agg_head<<<wave_grid, 256, 0, stream>>>(s, offs, cnt, srcs, dinv, b2, Wl, bl, out, n);
}

// Round 6
// 455.576 us; speedup vs baseline: 2.5104x; 1.1797x over previous
//
#include <hip/hip_runtime.h>
#include <math.h>

#define FDIM 128
#define BKT_BITS 8                 // 256 nodes per bucket
#define BKT_W (1 << BKT_BITS)
#define BIN_CHUNK 12544            // max edges per k_bin block (50 KB LDS)

typedef short bf16x8 __attribute__((ext_vector_type(8)));
typedef float f32x4 __attribute__((ext_vector_type(4)));

union ABu { bf16x8 v; unsigned int u[4]; };
union F4u { float4 f; float a[4]; };

__device__ inline unsigned int pack_bf16x2(float a, float b) {
  unsigned int ua = __float_as_uint(a);
  unsigned int ub = __float_as_uint(b);
  ua = (ua + 0x7fffu + ((ua >> 16) & 1u)) >> 16;   // RNE
  ub = (ub + 0x7fffu + ((ub >> 16) & 1u)) >> 16;
  return ua | (ub << 16);
}

// ---------------- CSR build: two-level binning ----------------

__global__ __launch_bounds__(256)
void k_bhist(const int* __restrict__ col, int* __restrict__ gbcnt, int nE, int nb) {
  __shared__ int lds[512];
  for (int i = threadIdx.x; i < 512; i += 256) lds[i] = 0;
  __syncthreads();
  int stride = gridDim.x * blockDim.x;
  for (int e = blockIdx.x * blockDim.x + threadIdx.x; e < nE; e += stride)
    atomicAdd(&lds[col[e] >> BKT_BITS], 1);
  __syncthreads();
  for (int b = threadIdx.x; b < nb; b += 256) {
    int c = lds[b];
    if (c) atomicAdd(&gbcnt[b], c);
  }
}

__global__ __launch_bounds__(512)
void k_bscan(const int* __restrict__ gbcnt, int* __restrict__ gboff,
             int* __restrict__ gcur, int nb, int nE) {
  __shared__ int lds[512];
  int t = threadIdx.x;
  lds[t] = (t < nb) ? gbcnt[t] : 0;
  __syncthreads();
  for (int off = 1; off < 512; off <<= 1) {
    int x = (t >= off) ? lds[t - off] : 0;
    __syncthreads();
    lds[t] += x;
    __syncthreads();
  }
  if (t < nb) {
    int excl = (t == 0) ? 0 : lds[t - 1];
    gboff[t] = excl;
    gcur[t] = excl;
  }
  if (t == 0) gboff[nb] = nE;
}

// level-1 scatter: packed (row | col_low<<24), bucket-contiguous.
__global__ __launch_bounds__(256)
void k_bin(const int* __restrict__ row, const int* __restrict__ col,
           int* __restrict__ gcur, int* __restrict__ pairs, int nE, int chunk, int nb) {
  __shared__ int bcnt[512];
  __shared__ int lcur[512];
  __shared__ int ecol[BIN_CHUNK];
  int e0 = blockIdx.x * chunk;
  int e1 = min(e0 + chunk, nE);
  int m = e1 - e0;
  for (int i = threadIdx.x; i < 512; i += 256) bcnt[i] = 0;
  for (int i = threadIdx.x; i < m; i += 256) ecol[i] = col[e0 + i];
  __syncthreads();
  for (int i = threadIdx.x; i < m; i += 256)
    atomicAdd(&bcnt[((unsigned)ecol[i]) >> BKT_BITS], 1);
  __syncthreads();
  for (int b = threadIdx.x; b < nb; b += 256) {
    int c = bcnt[b];
    lcur[b] = c ? atomicAdd(&gcur[b], c) : 0;
  }
  __syncthreads();
  for (int i = threadIdx.x; i < m; i += 256) {
    int c = ecol[i];
    int r = row[e0 + i];
    int p = atomicAdd(&lcur[((unsigned)c) >> BKT_BITS], 1);
    pairs[p] = r | ((c & (BKT_W - 1)) << 24);
  }
}

// fine pass: one block per bucket. cnt/offs/dinv + LDS-cursor scatter of rows.
__global__ __launch_bounds__(256)
void k_fine(const int* __restrict__ pairs, const int* __restrict__ gboff,
            int* __restrict__ srcs, int* __restrict__ offs, int* __restrict__ cnt,
            float* __restrict__ dinv, int n) {
  __shared__ int lcnt[256];
  __shared__ int lcur[256];
  int b = blockIdx.x;
  int t = threadIdx.x;
  int ebase = gboff[b];
  int eend = gboff[b + 1];
  lcnt[t] = 0;
  __syncthreads();
  for (int e = ebase + t; e < eend; e += 256)
    atomicAdd(&lcnt[((unsigned)pairs[e]) >> 24], 1);
  __syncthreads();
  int orig = lcnt[t];
  for (int off = 1; off < 256; off <<= 1) {
    int x = (t >= off) ? lcnt[t - off] : 0;
    __syncthreads();
    lcnt[t] += x;
    __syncthreads();
  }
  int excl = lcnt[t] - orig;
  int v = (b << BKT_BITS) + t;
  if (v < n) {
    offs[v] = ebase + excl;
    cnt[v] = orig;
    dinv[v] = rsqrtf((float)(orig + 1));  // +1 self loop
  }
  lcur[t] = ebase + excl;
  __syncthreads();
  for (int e = ebase + t; e < eend; e += 256) {
    int pr = pairs[e];
    int p = atomicAdd(&lcur[((unsigned)pr) >> 24], 1);
    srcs[p] = pr & 0x00FFFFFF;
  }
}

// ---------- MFMA GEMM: [n,128] x W[128,128], *dinv[row], bf16 out ----------
// W staged to LDS as W^T bf16, XOR-swizzled (unit ^= col&15 -> 2-way = free).
// Block: 256 thr = 4 waves, 16 rows/wave. A frag: lane holds row (l&15),
// k = (l>>4)*8..+7 per k-step. C/D: col = nt*16 + (l&15), row = rbase+(l>>4)*4+i.
#define STAGE_WT()                                                          \
  {                                                                         \
    int c = threadIdx.x & 127;                                              \
    for (int kp = (threadIdx.x >> 7); kp < 64; kp += 2) {                   \
      float w0 = W[(kp * 2) * 128 + c];                                     \
      float w1 = W[(kp * 2 + 1) * 128 + c];                                 \
      int unit = kp >> 2, dw = kp & 3;                                      \
      wlds[c * 64 + ((unit ^ (c & 15)) << 2) + dw] = pack_bf16x2(w0, w1);   \
    }                                                                       \
  }                                                                         \
  __syncthreads();

#define GEMM_BODY()                                                         \
  int l = threadIdx.x & 63;                                                 \
  int grp = l >> 4, c15 = l & 15;                                           \
  int rbase = blockIdx.x * 64 + (threadIdx.x >> 6) * 16;                    \
  F4u dv;                                                                   \
  dv.f = *(const float4*)(dinv + rbase + grp * 4);                          \
  f32x4 acc[8];                                                             \
  _Pragma("unroll")                                                         \
  for (int nt = 0; nt < 8; ++nt) acc[nt] = (f32x4){0.f, 0.f, 0.f, 0.f};    \
  _Pragma("unroll")                                                         \
  for (int nt = 0; nt < 8; ++nt) {                                          \
    _Pragma("unroll")                                                       \
    for (int ks = 0; ks < 4; ++ks) {                                        \
      ABu b;                                                                \
      b.v = *(const bf16x8*)&wlds[(nt * 16 + c15) * 64 +                    \
                                  ((((ks << 2) + grp) ^ c15) << 2)];        \
      acc[nt] = __builtin_amdgcn_mfma_f32_16x16x32_bf16(a[ks].v, b.v,       \
                                                        acc[nt], 0, 0, 0);  \
    }                                                                       \
  }                                                                         \
  _Pragma("unroll")                                                         \
  for (int nt = 0; nt < 8; ++nt) {                                          \
    _Pragma("unroll")                                                       \
    for (int i = 0; i < 4; ++i) {                                           \
      int r = rbase + grp * 4 + i;                                          \
      if (r < n) {                                                          \
        float v = acc[nt][i] * dv.a[i];                                     \
        out[(size_t)r * 128 + nt * 16 + c15] =                              \
            (unsigned short)(pack_bf16x2(v, 0.f) & 0xffffu);                \
      }                                                                     \
    }                                                                       \
  }

__global__ __launch_bounds__(256)
void k_gemm_mfma_f(const float* __restrict__ in, const float* __restrict__ W,
                   const float* __restrict__ dinv, unsigned short* __restrict__ out,
                   int n) {
  __shared__ unsigned int wlds[128 * 64];
  STAGE_WT();
  {
    int l0 = threadIdx.x & 63;
    int row = blockIdx.x * 64 + (threadIdx.x >> 6) * 16 + (l0 & 15);
    int rowc = min(row, n - 1);
    int grp0 = l0 >> 4;
    const float4* xr = (const float4*)(in + (size_t)rowc * 128);
    ABu a[4];
#pragma unroll
    for (int ks = 0; ks < 4; ++ks) {
      float4 f0 = xr[ks * 8 + grp0 * 2];
      float4 f1 = xr[ks * 8 + grp0 * 2 + 1];
      a[ks].u[0] = pack_bf16x2(f0.x, f0.y);
      a[ks].u[1] = pack_bf16x2(f0.z, f0.w);
      a[ks].u[2] = pack_bf16x2(f1.x, f1.y);
      a[ks].u[3] = pack_bf16x2(f1.z, f1.w);
    }
    GEMM_BODY();
  }
}

__global__ __launch_bounds__(256)
void k_gemm_mfma_b(const unsigned int* __restrict__ in, const float* __restrict__ W,
                   const float* __restrict__ dinv, unsigned short* __restrict__ out,
                   int n) {
  __shared__ unsigned int wlds[128 * 64];
  STAGE_WT();
  {
    int l0 = threadIdx.x & 63;
    int row = blockIdx.x * 64 + (threadIdx.x >> 6) * 16 + (l0 & 15);
    int rowc = min(row, n - 1);
    int grp0 = l0 >> 4;
    const unsigned int* hr = in + (size_t)rowc * 64;
    ABu a[4];
#pragma unroll
    for (int ks = 0; ks < 4; ++ks)
      a[ks].v = *(const bf16x8*)&hr[ks * 16 + grp0 * 4];
    GEMM_BODY();
  }
}

// ---------------- gather-accumulate core (one wave per node) ----------------
__device__ inline float2 agg_core(const unsigned int* __restrict__ sb,
                                  const int* __restrict__ offs,
                                  const int* __restrict__ cnt,
                                  const int* __restrict__ srcs,
                                  int v, int lane) {
  float2 acc;
  {
    unsigned int p = sb[(size_t)v * 64 + lane];  // self contribution
    acc.x = __uint_as_float(p << 16);
    acc.y = __uint_as_float(p & 0xffff0000u);
  }
  int beg = offs[v];
  int m = cnt[v];
  for (int base = 0; base < m; base += 64) {
    int take = m - base;
    if (take > 64) take = 64;
    int idx = (lane < take) ? srcs[beg + base + lane] : 0;
    int it = 0;
    for (; it + 7 < take; it += 8) {
      int u0 = __shfl(idx, it, 64);
      int u1 = __shfl(idx, it + 1, 64);
      int u2 = __shfl(idx, it + 2, 64);
      int u3 = __shfl(idx, it + 3, 64);
      int u4 = __shfl(idx, it + 4, 64);
      int u5 = __shfl(idx, it + 5, 64);
      int u6 = __shfl(idx, it + 6, 64);
      int u7 = __shfl(idx, it + 7, 64);
      unsigned int p0 = sb[(size_t)u0 * 64 + lane];
      unsigned int p1 = sb[(size_t)u1 * 64 + lane];
      unsigned int p2 = sb[(size_t)u2 * 64 + lane];
      unsigned int p3 = sb[(size_t)u3 * 64 + lane];
      unsigned int p4 = sb[(size_t)u4 * 64 + lane];
      unsigned int p5 = sb[(size_t)u5 * 64 + lane];
      unsigned int p6 = sb[(size_t)u6 * 64 + lane];
      unsigned int p7 = sb[(size_t)u7 * 64 + lane];
      acc.x += ((__uint_as_float(p0 << 16) + __uint_as_float(p1 << 16)) +
                (__uint_as_float(p2 << 16) + __uint_as_float(p3 << 16))) +
               ((__uint_as_float(p4 << 16) + __uint_as_float(p5 << 16)) +
                (__uint_as_float(p6 << 16) + __uint_as_float(p7 << 16)));
      acc.y += ((__uint_as_float(p0 & 0xffff0000u) + __uint_as_float(p1 & 0xffff0000u)) +
                (__uint_as_float(p2 & 0xffff0000u) + __uint_as_float(p3 & 0xffff0000u))) +
               ((__uint_as_float(p4 & 0xffff0000u) + __uint_as_float(p5 & 0xffff0000u)) +
                (__uint_as_float(p6 & 0xffff0000u) + __uint_as_float(p7 & 0xffff0000u)));
    }
    for (; it < take; ++it) {
      int u = __shfl(idx, it, 64);
      unsigned int p = sb[(size_t)u * 64 + lane];
      acc.x += __uint_as_float(p << 16);
      acc.y += __uint_as_float(p & 0xffff0000u);
    }
  }
  return acc;
}

// layer-1 aggregate: h = relu(dinv*(...)+b), stored bf16
__global__ __launch_bounds__(256)
void k_agg_mid(const unsigned int* __restrict__ sb, const int* __restrict__ offs,
               const int* __restrict__ cnt, const int* __restrict__ srcs,
               const float* __restrict__ dinv, const float* __restrict__ bias,
               unsigned int* __restrict__ hb, int n) {
  int v = (int)(((size_t)blockIdx.x * blockDim.x + threadIdx.x) >> 6);
  if (v >= n) return;
  int lane = threadIdx.x & 63;
  float2 acc = agg_core(sb, offs, cnt, srcs, v, lane);
  float d = dinv[v];
  float2 b = ((const float2*)bias)[lane];
  float rx = fmaxf(acc.x * d + b.x, 0.0f);
  float ry = fmaxf(acc.y * d + b.y, 0.0f);
  hb[(size_t)v * 64 + lane] = pack_bf16x2(rx, ry);
}

// layer-2 aggregate fused with head: out = sigmoid(relu(...)@Wl + bl)
__global__ __launch_bounds__(256)
void k_agg_head(const unsigned int* __restrict__ sb, const int* __restrict__ offs,
                const int* __restrict__ cnt, const int* __restrict__ srcs,
                const float* __restrict__ dinv, const float* __restrict__ bias,
                const float* __restrict__ Wl, const float* __restrict__ bl,
                float* __restrict__ out, int n) {
  int v = (int)(((size_t)blockIdx.x * blockDim.x + threadIdx.x) >> 6);
  if (v >= n) return;
  int lane = threadIdx.x & 63;
  float2 acc = agg_core(sb, offs, cnt, srcs, v, lane);
  float d = dinv[v];
  float2 b = ((const float2*)bias)[lane];
  float rx = fmaxf(acc.x * d + b.x, 0.0f);
  float ry = fmaxf(acc.y * d + b.y, 0.0f);
  float2 wv = ((const float2*)Wl)[lane];
  float p = rx * wv.x + ry * wv.y;
#pragma unroll
  for (int off = 32; off > 0; off >>= 1) p += __shfl_down(p, off, 64);
  if (lane == 0) {
    float z = p + bl[0];
    out[v] = 1.0f / (1.0f + expf(-z));
  }
}

// ---------------- launch ----------------

extern "C" void kernel_launch(void* const* d_in, const int* in_sizes, int n_in,
                              void* d_out, int out_size, void* d_ws, size_t ws_size,
                              hipStream_t stream) {
  const float* x  = (const float*)d_in[0];
  const int*   ei = (const int*)d_in[1];
  const float* W1 = (const float*)d_in[2];
  const float* b1 = (const float*)d_in[3];
  const float* W2 = (const float*)d_in[4];
  const float* b2 = (const float*)d_in[5];
  const float* Wl = (const float*)d_in[6];
  const float* bl = (const float*)d_in[7];
  float* out = (float*)d_out;

  int n  = in_sizes[0] / FDIM;   // 100000
  int nE = in_sizes[1] / 2;      // 3200000
  const int* row = ei;
  const int* col = ei + nE;
  int nb = (n + BKT_W - 1) >> BKT_BITS;   // 391

  // workspace carve (~66 MB); pairs aliases hb (hb first written after k_fine)
  unsigned int* s  = (unsigned int*)d_ws;          // n*64 dwords (bf16x2)
  unsigned int* hb = s + (size_t)n * 64;           // n*64 dwords (bf16x2)
  float* dinv  = (float*)(hb + (size_t)n * 64);    // n
  int*   cnt   = (int*)(dinv + n);                 // n
  int*   offs  = cnt + n;                          // n
  int*   srcs  = offs + n;                         // nE
  int*   gbcnt = srcs + nE;                        // nb
  int*   gboff = gbcnt + nb;                       // nb+1
  int*   gcur  = gboff + nb + 1;                   // nb
  int*   pairs = (int*)hb;                         // nE packed (aliased)

  hipMemsetAsync(gbcnt, 0, (size_t)nb * sizeof(int), stream);
  k_bhist<<<256, 256, 0, stream>>>(col, gbcnt, nE, nb);
  k_bscan<<<1, 512, 0, stream>>>(gbcnt, gboff, gcur, nb, nE);
  int chunk = (nE + 255) / 256;   // 12500 <= BIN_CHUNK
  k_bin<<<256, 256, 0, stream>>>(row, col, gcur, pairs, nE, chunk, nb);
  k_fine<<<nb, 256, 0, stream>>>(pairs, gboff, srcs, offs, cnt, dinv, n);

  int gemm_grid = (n + 63) / 64;  // 64 rows per block (4 waves x 16 rows)
  int wave_grid = (n + 3) / 4;    // 4 waves / 256-thread block
  k_gemm_mfma_f<<<gemm_grid, 256, 0, stream>>>(x, W1, dinv, (unsigned short*)s, n);
  k_agg_mid<<<wave_grid, 256, 0, stream>>>(s, offs, cnt, srcs, dinv, b1, hb, n);
  k_gemm_mfma_b<<<gemm_grid, 256, 0, stream>>>(hb, W2, dinv, (unsigned short*)s, n);
  k_agg_head<<<wave_grid, 256, 0, stream>>>(s, offs, cnt, srcs, dinv, b2, Wl, bl, out, n);
}

// Round 7
// 379.820 us; speedup vs baseline: 3.0111x; 1.1995x over previous
//
#include <hip/hip_runtime.h>
#include <math.h>

#define FDIM 128
#define BKT_BITS 8                 // 256 nodes per bucket
#define BKT_W (1 << BKT_BITS)
#define BIN_CHUNK 12544            // max edges per k_bin block (50 KB LDS)

typedef short bf16x8 __attribute__((ext_vector_type(8)));
typedef float f32x4 __attribute__((ext_vector_type(4)));
typedef float f32x2 __attribute__((ext_vector_type(2)));

union ABu { bf16x8 v; unsigned int u[4]; };
union F4u { float4 f; float a[4]; };

__device__ inline unsigned int pack_bf16x2(float a, float b) {
  unsigned int ua = __float_as_uint(a);
  unsigned int ub = __float_as_uint(b);
  ua = (ua + 0x7fffu + ((ua >> 16) & 1u)) >> 16;   // RNE
  ub = (ub + 0x7fffu + ((ub >> 16) & 1u)) >> 16;
  return ua | (ub << 16);
}

// fp8 e4m3 (OCP on gfx950) helpers — hardware converts
__device__ inline unsigned char f32_to_fp8(float v) {
  return (unsigned char)(__builtin_amdgcn_cvt_pk_fp8_f32(v, v, 0, false) & 0xff);
}
__device__ inline float2 fp8x2_to_f32(unsigned int u) {
  f32x2 r = __builtin_amdgcn_cvt_pk_f32_fp8((int)u, false);
  return make_float2(r[0], r[1]);
}

// ---------------- CSR build: two-level binning ----------------

__global__ __launch_bounds__(256)
void k_bhist(const int* __restrict__ col, int* __restrict__ gbcnt, int nE, int nb) {
  __shared__ int lds[512];
  for (int i = threadIdx.x; i < 512; i += 256) lds[i] = 0;
  __syncthreads();
  int stride = gridDim.x * blockDim.x;
  for (int e = blockIdx.x * blockDim.x + threadIdx.x; e < nE; e += stride)
    atomicAdd(&lds[col[e] >> BKT_BITS], 1);
  __syncthreads();
  for (int b = threadIdx.x; b < nb; b += 256) {
    int c = lds[b];
    if (c) atomicAdd(&gbcnt[b], c);
  }
}

__global__ __launch_bounds__(512)
void k_bscan(const int* __restrict__ gbcnt, int* __restrict__ gboff,
             int* __restrict__ gcur, int nb, int nE) {
  __shared__ int lds[512];
  int t = threadIdx.x;
  lds[t] = (t < nb) ? gbcnt[t] : 0;
  __syncthreads();
  for (int off = 1; off < 512; off <<= 1) {
    int x = (t >= off) ? lds[t - off] : 0;
    __syncthreads();
    lds[t] += x;
    __syncthreads();
  }
  if (t < nb) {
    int excl = (t == 0) ? 0 : lds[t - 1];
    gboff[t] = excl;
    gcur[t] = excl;
  }
  if (t == 0) gboff[nb] = nE;
}

// level-1 scatter: packed (row | col_low<<24), bucket-contiguous.
__global__ __launch_bounds__(256)
void k_bin(const int* __restrict__ row, const int* __restrict__ col,
           int* __restrict__ gcur, int* __restrict__ pairs, int nE, int chunk, int nb) {
  __shared__ int bcnt[512];
  __shared__ int lcur[512];
  __shared__ int ecol[BIN_CHUNK];
  int e0 = blockIdx.x * chunk;
  int e1 = min(e0 + chunk, nE);
  int m = e1 - e0;
  for (int i = threadIdx.x; i < 512; i += 256) bcnt[i] = 0;
  for (int i = threadIdx.x; i < m; i += 256) ecol[i] = col[e0 + i];
  __syncthreads();
  for (int i = threadIdx.x; i < m; i += 256)
    atomicAdd(&bcnt[((unsigned)ecol[i]) >> BKT_BITS], 1);
  __syncthreads();
  for (int b = threadIdx.x; b < nb; b += 256) {
    int c = bcnt[b];
    lcur[b] = c ? atomicAdd(&gcur[b], c) : 0;
  }
  __syncthreads();
  for (int i = threadIdx.x; i < m; i += 256) {
    int c = ecol[i];
    int r = row[e0 + i];
    int p = atomicAdd(&lcur[((unsigned)c) >> BKT_BITS], 1);
    pairs[p] = r | ((c & (BKT_W - 1)) << 24);
  }
}

// fine pass: one block per bucket. cnt/offs/dinv + LDS-cursor scatter of rows.
__global__ __launch_bounds__(256)
void k_fine(const int* __restrict__ pairs, const int* __restrict__ gboff,
            int* __restrict__ srcs, int* __restrict__ offs, int* __restrict__ cnt,
            float* __restrict__ dinv, int n) {
  __shared__ int lcnt[256];
  __shared__ int lcur[256];
  int b = blockIdx.x;
  int t = threadIdx.x;
  int ebase = gboff[b];
  int eend = gboff[b + 1];
  lcnt[t] = 0;
  __syncthreads();
  for (int e = ebase + t; e < eend; e += 256)
    atomicAdd(&lcnt[((unsigned)pairs[e]) >> 24], 1);
  __syncthreads();
  int orig = lcnt[t];
  for (int off = 1; off < 256; off <<= 1) {
    int x = (t >= off) ? lcnt[t - off] : 0;
    __syncthreads();
    lcnt[t] += x;
    __syncthreads();
  }
  int excl = lcnt[t] - orig;
  int v = (b << BKT_BITS) + t;
  if (v < n) {
    offs[v] = ebase + excl;
    cnt[v] = orig;
    dinv[v] = rsqrtf((float)(orig + 1));  // +1 self loop
  }
  lcur[t] = ebase + excl;
  __syncthreads();
  for (int e = ebase + t; e < eend; e += 256) {
    int pr = pairs[e];
    int p = atomicAdd(&lcur[((unsigned)pr) >> 24], 1);
    srcs[p] = pr & 0x00FFFFFF;
  }
}

// ---------- MFMA GEMM: [n,128] x W[128,128], *dinv[row], fp8 out ----------
// W staged to LDS as W^T bf16, XOR-swizzled (unit ^= col&15 -> 2-way = free).
// Block: 256 thr = 4 waves, 16 rows/wave. A frag: lane holds row (l&15),
// k = (l>>4)*8..+7 per k-step. C/D: col = nt*16 + (l&15), row = rbase+(l>>4)*4+i.
#define STAGE_WT()                                                          \
  {                                                                         \
    int c = threadIdx.x & 127;                                              \
    for (int kp = (threadIdx.x >> 7); kp < 64; kp += 2) {                   \
      float w0 = W[(kp * 2) * 128 + c];                                     \
      float w1 = W[(kp * 2 + 1) * 128 + c];                                 \
      int unit = kp >> 2, dw = kp & 3;                                      \
      wlds[c * 64 + ((unit ^ (c & 15)) << 2) + dw] = pack_bf16x2(w0, w1);   \
    }                                                                       \
  }                                                                         \
  __syncthreads();

#define GEMM_BODY()                                                         \
  int l = threadIdx.x & 63;                                                 \
  int grp = l >> 4, c15 = l & 15;                                           \
  int rbase = blockIdx.x * 64 + (threadIdx.x >> 6) * 16;                    \
  F4u dv;                                                                   \
  dv.f = *(const float4*)(dinv + rbase + grp * 4);                          \
  f32x4 acc[8];                                                             \
  _Pragma("unroll")                                                         \
  for (int nt = 0; nt < 8; ++nt) acc[nt] = (f32x4){0.f, 0.f, 0.f, 0.f};    \
  _Pragma("unroll")                                                         \
  for (int nt = 0; nt < 8; ++nt) {                                          \
    _Pragma("unroll")                                                       \
    for (int ks = 0; ks < 4; ++ks) {                                        \
      ABu b;                                                                \
      b.v = *(const bf16x8*)&wlds[(nt * 16 + c15) * 64 +                    \
                                  ((((ks << 2) + grp) ^ c15) << 2)];        \
      acc[nt] = __builtin_amdgcn_mfma_f32_16x16x32_bf16(a[ks].v, b.v,       \
                                                        acc[nt], 0, 0, 0);  \
    }                                                                       \
  }                                                                         \
  _Pragma("unroll")                                                         \
  for (int nt = 0; nt < 8; ++nt) {                                          \
    _Pragma("unroll")                                                       \
    for (int i = 0; i < 4; ++i) {                                           \
      int r = rbase + grp * 4 + i;                                          \
      if (r < n) {                                                          \
        float v = acc[nt][i] * dv.a[i];                                     \
        out[(size_t)r * 128 + nt * 16 + c15] = f32_to_fp8(v);               \
      }                                                                     \
    }                                                                       \
  }

__global__ __launch_bounds__(256)
void k_gemm_mfma_f(const float* __restrict__ in, const float* __restrict__ W,
                   const float* __restrict__ dinv, unsigned char* __restrict__ out,
                   int n) {
  __shared__ unsigned int wlds[128 * 64];
  STAGE_WT();
  {
    int l0 = threadIdx.x & 63;
    int row = blockIdx.x * 64 + (threadIdx.x >> 6) * 16 + (l0 & 15);
    int rowc = min(row, n - 1);
    int grp0 = l0 >> 4;
    const float4* xr = (const float4*)(in + (size_t)rowc * 128);
    ABu a[4];
#pragma unroll
    for (int ks = 0; ks < 4; ++ks) {
      float4 f0 = xr[ks * 8 + grp0 * 2];
      float4 f1 = xr[ks * 8 + grp0 * 2 + 1];
      a[ks].u[0] = pack_bf16x2(f0.x, f0.y);
      a[ks].u[1] = pack_bf16x2(f0.z, f0.w);
      a[ks].u[2] = pack_bf16x2(f1.x, f1.y);
      a[ks].u[3] = pack_bf16x2(f1.z, f1.w);
    }
    GEMM_BODY();
  }
}

__global__ __launch_bounds__(256)
void k_gemm_mfma_b(const unsigned int* __restrict__ in, const float* __restrict__ W,
                   const float* __restrict__ dinv, unsigned char* __restrict__ out,
                   int n) {
  __shared__ unsigned int wlds[128 * 64];
  STAGE_WT();
  {
    int l0 = threadIdx.x & 63;
    int row = blockIdx.x * 64 + (threadIdx.x >> 6) * 16 + (l0 & 15);
    int rowc = min(row, n - 1);
    int grp0 = l0 >> 4;
    const unsigned int* hr = in + (size_t)rowc * 64;
    ABu a[4];
#pragma unroll
    for (int ks = 0; ks < 4; ++ks)
      a[ks].v = *(const bf16x8*)&hr[ks * 16 + grp0 * 4];
    GEMM_BODY();
  }
}

// ------------ gather-accumulate core (one wave per node, fp8 rows) ------------
__device__ inline float2 agg_core(const unsigned short* __restrict__ sb,
                                  const int* __restrict__ offs,
                                  const int* __restrict__ cnt,
                                  const int* __restrict__ srcs,
                                  int v, int lane) {
  float2 acc;
  {
    float2 d = fp8x2_to_f32(sb[(size_t)v * 64 + lane]);  // self contribution
    acc = d;
  }
  int beg = offs[v];
  int m = cnt[v];
  for (int base = 0; base < m; base += 64) {
    int take = m - base;
    if (take > 64) take = 64;
    int idx = (lane < take) ? srcs[beg + base + lane] : 0;
    int it = 0;
    for (; it + 7 < take; it += 8) {
      int u0 = __shfl(idx, it, 64);
      int u1 = __shfl(idx, it + 1, 64);
      int u2 = __shfl(idx, it + 2, 64);
      int u3 = __shfl(idx, it + 3, 64);
      int u4 = __shfl(idx, it + 4, 64);
      int u5 = __shfl(idx, it + 5, 64);
      int u6 = __shfl(idx, it + 6, 64);
      int u7 = __shfl(idx, it + 7, 64);
      unsigned short p0 = sb[(size_t)u0 * 64 + lane];
      unsigned short p1 = sb[(size_t)u1 * 64 + lane];
      unsigned short p2 = sb[(size_t)u2 * 64 + lane];
      unsigned short p3 = sb[(size_t)u3 * 64 + lane];
      unsigned short p4 = sb[(size_t)u4 * 64 + lane];
      unsigned short p5 = sb[(size_t)u5 * 64 + lane];
      unsigned short p6 = sb[(size_t)u6 * 64 + lane];
      unsigned short p7 = sb[(size_t)u7 * 64 + lane];
      float2 d0 = fp8x2_to_f32(p0);
      float2 d1 = fp8x2_to_f32(p1);
      float2 d2 = fp8x2_to_f32(p2);
      float2 d3 = fp8x2_to_f32(p3);
      float2 d4 = fp8x2_to_f32(p4);
      float2 d5 = fp8x2_to_f32(p5);
      float2 d6 = fp8x2_to_f32(p6);
      float2 d7 = fp8x2_to_f32(p7);
      acc.x += ((d0.x + d1.x) + (d2.x + d3.x)) + ((d4.x + d5.x) + (d6.x + d7.x));
      acc.y += ((d0.y + d1.y) + (d2.y + d3.y)) + ((d4.y + d5.y) + (d6.y + d7.y));
    }
    for (; it < take; ++it) {
      int u = __shfl(idx, it, 64);
      float2 d = fp8x2_to_f32(sb[(size_t)u * 64 + lane]);
      acc.x += d.x;
      acc.y += d.y;
    }
  }
  return acc;
}

// layer-1 aggregate: h = relu(dinv*(...)+b), stored bf16 (coalesced reader)
__global__ __launch_bounds__(256)
void k_agg_mid(const unsigned short* __restrict__ sb, const int* __restrict__ offs,
               const int* __restrict__ cnt, const int* __restrict__ srcs,
               const float* __restrict__ dinv, const float* __restrict__ bias,
               unsigned int* __restrict__ hb, int n) {
  int v = (int)(((size_t)blockIdx.x * blockDim.x + threadIdx.x) >> 6);
  if (v >= n) return;
  int lane = threadIdx.x & 63;
  float2 acc = agg_core(sb, offs, cnt, srcs, v, lane);
  float d = dinv[v];
  float2 b = ((const float2*)bias)[lane];
  float rx = fmaxf(acc.x * d + b.x, 0.0f);
  float ry = fmaxf(acc.y * d + b.y, 0.0f);
  hb[(size_t)v * 64 + lane] = pack_bf16x2(rx, ry);
}

// layer-2 aggregate fused with head: out = sigmoid(relu(...)@Wl + bl)
__global__ __launch_bounds__(256)
void k_agg_head(const unsigned short* __restrict__ sb, const int* __restrict__ offs,
                const int* __restrict__ cnt, const int* __restrict__ srcs,
                const float* __restrict__ dinv, const float* __restrict__ bias,
                const float* __restrict__ Wl, const float* __restrict__ bl,
                float* __restrict__ out, int n) {
  int v = (int)(((size_t)blockIdx.x * blockDim.x + threadIdx.x) >> 6);
  if (v >= n) return;
  int lane = threadIdx.x & 63;
  float2 acc = agg_core(sb, offs, cnt, srcs, v, lane);
  float d = dinv[v];
  float2 b = ((const float2*)bias)[lane];
  float rx = fmaxf(acc.x * d + b.x, 0.0f);
  float ry = fmaxf(acc.y * d + b.y, 0.0f);
  float2 wv = ((const float2*)Wl)[lane];
  float p = rx * wv.x + ry * wv.y;
#pragma unroll
  for (int off = 32; off > 0; off >>= 1) p += __shfl_down(p, off, 64);
  if (lane == 0) {
    float z = p + bl[0];
    out[v] = 1.0f / (1.0f + expf(-z));
  }
}

// ---------------- launch ----------------

extern "C" void kernel_launch(void* const* d_in, const int* in_sizes, int n_in,
                              void* d_out, int out_size, void* d_ws, size_t ws_size,
                              hipStream_t stream) {
  const float* x  = (const float*)d_in[0];
  const int*   ei = (const int*)d_in[1];
  const float* W1 = (const float*)d_in[2];
  const float* b1 = (const float*)d_in[3];
  const float* W2 = (const float*)d_in[4];
  const float* b2 = (const float*)d_in[5];
  const float* Wl = (const float*)d_in[6];
  const float* bl = (const float*)d_in[7];
  float* out = (float*)d_out;

  int n  = in_sizes[0] / FDIM;   // 100000
  int nE = in_sizes[1] / 2;      // 3200000
  const int* row = ei;
  const int* col = ei + nE;
  int nb = (n + BKT_W - 1) >> BKT_BITS;   // 391

  // workspace carve (~53 MB); pairs aliases hb (hb first written after k_fine)
  unsigned char* s8 = (unsigned char*)d_ws;             // n*128 bytes (fp8)
  unsigned int* hb  = (unsigned int*)(s8 + (size_t)n * 128); // n*64 dwords (bf16x2)
  float* dinv  = (float*)(hb + (size_t)n * 64);         // n
  int*   cnt   = (int*)(dinv + n);                      // n
  int*   offs  = cnt + n;                               // n
  int*   srcs  = offs + n;                              // nE
  int*   gbcnt = srcs + nE;                             // nb
  int*   gboff = gbcnt + nb;                            // nb+1
  int*   gcur  = gboff + nb + 1;                        // nb
  int*   pairs = (int*)hb;                              // nE packed (aliased)

  hipMemsetAsync(gbcnt, 0, (size_t)nb * sizeof(int), stream);
  k_bhist<<<256, 256, 0, stream>>>(col, gbcnt, nE, nb);
  k_bscan<<<1, 512, 0, stream>>>(gbcnt, gboff, gcur, nb, nE);
  int chunk = (nE + 255) / 256;   // 12500 <= BIN_CHUNK
  k_bin<<<256, 256, 0, stream>>>(row, col, gcur, pairs, nE, chunk, nb);
  k_fine<<<nb, 256, 0, stream>>>(pairs, gboff, srcs, offs, cnt, dinv, n);

  int gemm_grid = (n + 63) / 64;  // 64 rows per block (4 waves x 16 rows)
  int wave_grid = (n + 3) / 4;    // 4 waves / 256-thread block
  k_gemm_mfma_f<<<gemm_grid, 256, 0, stream>>>(x, W1, dinv, s8, n);
  k_agg_mid<<<wave_grid, 256, 0, stream>>>((const unsigned short*)s8, offs, cnt, srcs, dinv, b1, hb, n);
  k_gemm_mfma_b<<<gemm_grid, 256, 0, stream>>>(hb, W2, dinv, s8, n);
  k_agg_head<<<wave_grid, 256, 0, stream>>>((const unsigned short*)s8, offs, cnt, srcs, dinv, b2, Wl, bl, out, n);
}

// Round 8
// 375.055 us; speedup vs baseline: 3.0494x; 1.0127x over previous
//
#include <hip/hip_runtime.h>
#include <math.h>

#define FDIM 128
#define BKT_BITS 8                 // 256 nodes per bucket
#define BKT_W (1 << BKT_BITS)
#define BIN_CHUNK 6272             // max edges per k_bin block (512-block grid)

typedef short bf16x8 __attribute__((ext_vector_type(8)));
typedef float f32x4 __attribute__((ext_vector_type(4)));
typedef float f32x2 __attribute__((ext_vector_type(2)));

union ABu { bf16x8 v; unsigned int u[4]; };
union F4u { float4 f; float a[4]; };

__device__ inline unsigned int pack_bf16x2(float a, float b) {
  unsigned int ua = __float_as_uint(a);
  unsigned int ub = __float_as_uint(b);
  ua = (ua + 0x7fffu + ((ua >> 16) & 1u)) >> 16;   // RNE
  ub = (ub + 0x7fffu + ((ub >> 16) & 1u)) >> 16;
  return ua | (ub << 16);
}

// fp8 e4m3 (OCP on gfx950) helpers — hardware converts
__device__ inline unsigned char f32_to_fp8(float v) {
  return (unsigned char)(__builtin_amdgcn_cvt_pk_fp8_f32(v, v, 0, false) & 0xff);
}

// ---------------- CSR build: two-level binning ----------------

__global__ __launch_bounds__(256)
void k_bhist(const int* __restrict__ col, int* __restrict__ gbcnt, int nE, int nb) {
  __shared__ int lds[512];
  for (int i = threadIdx.x; i < 512; i += 256) lds[i] = 0;
  __syncthreads();
  int stride = gridDim.x * blockDim.x;
  for (int e = blockIdx.x * blockDim.x + threadIdx.x; e < nE; e += stride)
    atomicAdd(&lds[col[e] >> BKT_BITS], 1);
  __syncthreads();
  for (int b = threadIdx.x; b < nb; b += 256) {
    int c = lds[b];
    if (c) atomicAdd(&gbcnt[b], c);
  }
}

__global__ __launch_bounds__(512)
void k_bscan(const int* __restrict__ gbcnt, int* __restrict__ gboff,
             int* __restrict__ gcur, int nb, int nE) {
  __shared__ int lds[512];
  int t = threadIdx.x;
  lds[t] = (t < nb) ? gbcnt[t] : 0;
  __syncthreads();
  for (int off = 1; off < 512; off <<= 1) {
    int x = (t >= off) ? lds[t - off] : 0;
    __syncthreads();
    lds[t] += x;
    __syncthreads();
  }
  if (t < nb) {
    int excl = (t == 0) ? 0 : lds[t - 1];
    gboff[t] = excl;
    gcur[t] = excl;
  }
  if (t == 0) gboff[nb] = nE;
}

// level-1 scatter: packed (row | col_low<<24), bucket-contiguous.
__global__ __launch_bounds__(256)
void k_bin(const int* __restrict__ row, const int* __restrict__ col,
           int* __restrict__ gcur, int* __restrict__ pairs, int nE, int chunk, int nb) {
  __shared__ int bcnt[512];
  __shared__ int lcur[512];
  __shared__ int ecol[BIN_CHUNK];
  int e0 = blockIdx.x * chunk;
  int e1 = min(e0 + chunk, nE);
  int m = e1 - e0;
  for (int i = threadIdx.x; i < 512; i += 256) bcnt[i] = 0;
  for (int i = threadIdx.x; i < m; i += 256) ecol[i] = col[e0 + i];
  __syncthreads();
  for (int i = threadIdx.x; i < m; i += 256)
    atomicAdd(&bcnt[((unsigned)ecol[i]) >> BKT_BITS], 1);
  __syncthreads();
  for (int b = threadIdx.x; b < nb; b += 256) {
    int c = bcnt[b];
    lcur[b] = c ? atomicAdd(&gcur[b], c) : 0;
  }
  __syncthreads();
  for (int i = threadIdx.x; i < m; i += 256) {
    int c = ecol[i];
    int r = row[e0 + i];
    int p = atomicAdd(&lcur[((unsigned)c) >> BKT_BITS], 1);
    pairs[p] = r | ((c & (BKT_W - 1)) << 24);
  }
}

// fine pass: one block (1024 thr) per bucket. cnt/offs/dinv + LDS-cursor scatter.
__global__ __launch_bounds__(1024)
void k_fine(const int* __restrict__ pairs, const int* __restrict__ gboff,
            int* __restrict__ srcs, int* __restrict__ offs, int* __restrict__ cnt,
            float* __restrict__ dinv, int n) {
  __shared__ int lcnt[256];
  __shared__ int lcur[256];
  int b = blockIdx.x;
  int t = threadIdx.x;
  int ebase = gboff[b];
  int eend = gboff[b + 1];
  if (t < 256) lcnt[t] = 0;
  __syncthreads();
  for (int e = ebase + t; e < eend; e += 1024)
    atomicAdd(&lcnt[((unsigned)pairs[e]) >> 24], 1);
  __syncthreads();
  int orig = (t < 256) ? lcnt[t] : 0;
  for (int off = 1; off < 256; off <<= 1) {
    int x = (t < 256 && t >= off) ? lcnt[t - off] : 0;
    __syncthreads();
    if (t < 256) lcnt[t] += x;
    __syncthreads();
  }
  if (t < 256) {
    int excl = lcnt[t] - orig;
    int v = (b << BKT_BITS) + t;
    if (v < n) {
      offs[v] = ebase + excl;
      cnt[v] = orig;
      dinv[v] = rsqrtf((float)(orig + 1));  // +1 self loop
    }
    lcur[t] = ebase + excl;
  }
  __syncthreads();
  for (int e = ebase + t; e < eend; e += 1024) {
    int pr = pairs[e];
    int p = atomicAdd(&lcur[((unsigned)pr) >> 24], 1);
    srcs[p] = pr & 0x00FFFFFF;
  }
}

// ---------- MFMA GEMM: [n,128] x W[128,128], *dinv[row], fp8 out ----------
// W staged to LDS as W^T bf16, XOR-swizzled (unit ^= col&15 -> 2-way = free).
#define STAGE_WT()                                                          \
  {                                                                         \
    int c = threadIdx.x & 127;                                              \
    for (int kp = (threadIdx.x >> 7); kp < 64; kp += 2) {                   \
      float w0 = W[(kp * 2) * 128 + c];                                     \
      float w1 = W[(kp * 2 + 1) * 128 + c];                                 \
      int unit = kp >> 2, dw = kp & 3;                                      \
      wlds[c * 64 + ((unit ^ (c & 15)) << 2) + dw] = pack_bf16x2(w0, w1);   \
    }                                                                       \
  }                                                                         \
  __syncthreads();

#define GEMM_BODY()                                                         \
  int l = threadIdx.x & 63;                                                 \
  int grp = l >> 4, c15 = l & 15;                                           \
  int rbase = blockIdx.x * 64 + (threadIdx.x >> 6) * 16;                    \
  F4u dv;                                                                   \
  dv.f = *(const float4*)(dinv + rbase + grp * 4);                          \
  f32x4 acc[8];                                                             \
  _Pragma("unroll")                                                         \
  for (int nt = 0; nt < 8; ++nt) acc[nt] = (f32x4){0.f, 0.f, 0.f, 0.f};    \
  _Pragma("unroll")                                                         \
  for (int nt = 0; nt < 8; ++nt) {                                          \
    _Pragma("unroll")                                                       \
    for (int ks = 0; ks < 4; ++ks) {                                        \
      ABu b;                                                                \
      b.v = *(const bf16x8*)&wlds[(nt * 16 + c15) * 64 +                    \
                                  ((((ks << 2) + grp) ^ c15) << 2)];        \
      acc[nt] = __builtin_amdgcn_mfma_f32_16x16x32_bf16(a[ks].v, b.v,       \
                                                        acc[nt], 0, 0, 0);  \
    }                                                                       \
  }                                                                         \
  _Pragma("unroll")                                                         \
  for (int nt = 0; nt < 8; ++nt) {                                          \
    _Pragma("unroll")                                                       \
    for (int i = 0; i < 4; ++i) {                                           \
      int r = rbase + grp * 4 + i;                                          \
      if (r < n) {                                                          \
        float v = acc[nt][i] * dv.a[i];                                     \
        out[(size_t)r * 128 + nt * 16 + c15] = f32_to_fp8(v);               \
      }                                                                     \
    }                                                                       \
  }

__global__ __launch_bounds__(256)
void k_gemm_mfma_f(const float* __restrict__ in, const float* __restrict__ W,
                   const float* __restrict__ dinv, unsigned char* __restrict__ out,
                   int n) {
  __shared__ unsigned int wlds[128 * 64];
  STAGE_WT();
  {
    int l0 = threadIdx.x & 63;
    int row = blockIdx.x * 64 + (threadIdx.x >> 6) * 16 + (l0 & 15);
    int rowc = min(row, n - 1);
    int grp0 = l0 >> 4;
    const float4* xr = (const float4*)(in + (size_t)rowc * 128);
    ABu a[4];
#pragma unroll
    for (int ks = 0; ks < 4; ++ks) {
      float4 f0 = xr[ks * 8 + grp0 * 2];
      float4 f1 = xr[ks * 8 + grp0 * 2 + 1];
      a[ks].u[0] = pack_bf16x2(f0.x, f0.y);
      a[ks].u[1] = pack_bf16x2(f0.z, f0.w);
      a[ks].u[2] = pack_bf16x2(f1.x, f1.y);
      a[ks].u[3] = pack_bf16x2(f1.z, f1.w);
    }
    GEMM_BODY();
  }
}

__global__ __launch_bounds__(256)
void k_gemm_mfma_b(const unsigned int* __restrict__ in, const float* __restrict__ W,
                   const float* __restrict__ dinv, unsigned char* __restrict__ out,
                   int n) {
  __shared__ unsigned int wlds[128 * 64];
  STAGE_WT();
  {
    int l0 = threadIdx.x & 63;
    int row = blockIdx.x * 64 + (threadIdx.x >> 6) * 16 + (l0 & 15);
    int rowc = min(row, n - 1);
    int grp0 = l0 >> 4;
    const unsigned int* hr = in + (size_t)rowc * 64;
    ABu a[4];
#pragma unroll
    for (int ks = 0; ks < 4; ++ks)
      a[ks].v = *(const bf16x8*)&hr[ks * 16 + grp0 * 4];
    GEMM_BODY();
  }
}

// ------ gather-accumulate core: wave/node, dword/lane, 2 rows per iter ------
// Half-wave hf=lane>>5 gathers its own row; lane owns cols cl*4..cl*4+3.
__device__ inline float4 agg_core(const unsigned int* __restrict__ s4,
                                  const int* __restrict__ offs,
                                  const int* __restrict__ cnt,
                                  const int* __restrict__ srcs,
                                  int v, int lane) {
  int cl = lane & 31;
  int hf = lane >> 5;
  float4 acc = make_float4(0.f, 0.f, 0.f, 0.f);
  if (lane < 32) {  // self contribution counted once
    unsigned int q = s4[(size_t)v * 32 + cl];
    f32x2 lo = __builtin_amdgcn_cvt_pk_f32_fp8((int)q, false);
    f32x2 hi = __builtin_amdgcn_cvt_pk_f32_fp8((int)q, true);
    acc = make_float4(lo[0], lo[1], hi[0], hi[1]);
  }
  int beg = offs[v];
  int m = cnt[v];
  for (int base = 0; base < m; base += 64) {
    int take = m - base;
    if (take > 64) take = 64;
    int idx = (lane < take) ? srcs[beg + base + lane] : 0;
    int it = 0;
    for (; it + 7 < take; it += 8) {
      int u0 = __shfl(idx, it + hf, 64);
      int u1 = __shfl(idx, it + 2 + hf, 64);
      int u2 = __shfl(idx, it + 4 + hf, 64);
      int u3 = __shfl(idx, it + 6 + hf, 64);
      unsigned int q0 = s4[(size_t)u0 * 32 + cl];
      unsigned int q1 = s4[(size_t)u1 * 32 + cl];
      unsigned int q2 = s4[(size_t)u2 * 32 + cl];
      unsigned int q3 = s4[(size_t)u3 * 32 + cl];
      f32x2 l0 = __builtin_amdgcn_cvt_pk_f32_fp8((int)q0, false);
      f32x2 h0 = __builtin_amdgcn_cvt_pk_f32_fp8((int)q0, true);
      f32x2 l1 = __builtin_amdgcn_cvt_pk_f32_fp8((int)q1, false);
      f32x2 h1 = __builtin_amdgcn_cvt_pk_f32_fp8((int)q1, true);
      f32x2 l2 = __builtin_amdgcn_cvt_pk_f32_fp8((int)q2, false);
      f32x2 h2 = __builtin_amdgcn_cvt_pk_f32_fp8((int)q2, true);
      f32x2 l3 = __builtin_amdgcn_cvt_pk_f32_fp8((int)q3, false);
      f32x2 h3 = __builtin_amdgcn_cvt_pk_f32_fp8((int)q3, true);
      acc.x += (l0[0] + l1[0]) + (l2[0] + l3[0]);
      acc.y += (l0[1] + l1[1]) + (l2[1] + l3[1]);
      acc.z += (h0[0] + h1[0]) + (h2[0] + h3[0]);
      acc.w += (h0[1] + h1[1]) + (h2[1] + h3[1]);
    }
    for (; it + 1 < take; it += 2) {
      int u = __shfl(idx, it + hf, 64);
      unsigned int q = s4[(size_t)u * 32 + cl];
      f32x2 lo = __builtin_amdgcn_cvt_pk_f32_fp8((int)q, false);
      f32x2 hi = __builtin_amdgcn_cvt_pk_f32_fp8((int)q, true);
      acc.x += lo[0]; acc.y += lo[1]; acc.z += hi[0]; acc.w += hi[1];
    }
    if (it < take) {  // odd tail: low half only
      int u = __shfl(idx, it, 64);
      if (lane < 32) {
        unsigned int q = s4[(size_t)u * 32 + cl];
        f32x2 lo = __builtin_amdgcn_cvt_pk_f32_fp8((int)q, false);
        f32x2 hi = __builtin_amdgcn_cvt_pk_f32_fp8((int)q, true);
        acc.x += lo[0]; acc.y += lo[1]; acc.z += hi[0]; acc.w += hi[1];
      }
    }
  }
  // combine the two half-wave partials
  acc.x += __shfl_xor(acc.x, 32, 64);
  acc.y += __shfl_xor(acc.y, 32, 64);
  acc.z += __shfl_xor(acc.z, 32, 64);
  acc.w += __shfl_xor(acc.w, 32, 64);
  return acc;
}

// layer-1 aggregate: h = relu(dinv*(...)+b), stored bf16 (coalesced reader)
__global__ __launch_bounds__(256)
void k_agg_mid(const unsigned int* __restrict__ s4, const int* __restrict__ offs,
               const int* __restrict__ cnt, const int* __restrict__ srcs,
               const float* __restrict__ dinv, const float* __restrict__ bias,
               unsigned int* __restrict__ hb, int n) {
  int v = (int)(((size_t)blockIdx.x * blockDim.x + threadIdx.x) >> 6);
  if (v >= n) return;
  int lane = threadIdx.x & 63;
  float4 acc = agg_core(s4, offs, cnt, srcs, v, lane);
  if (lane < 32) {
    int cl = lane;
    float d = dinv[v];
    float4 bb = ((const float4*)bias)[cl];
    float r0 = fmaxf(acc.x * d + bb.x, 0.0f);
    float r1 = fmaxf(acc.y * d + bb.y, 0.0f);
    float r2 = fmaxf(acc.z * d + bb.z, 0.0f);
    float r3 = fmaxf(acc.w * d + bb.w, 0.0f);
    uint2 pk;
    pk.x = pack_bf16x2(r0, r1);
    pk.y = pack_bf16x2(r2, r3);
    ((uint2*)hb)[(size_t)v * 32 + cl] = pk;
  }
}

// layer-2 aggregate fused with head: out = sigmoid(relu(...)@Wl + bl)
__global__ __launch_bounds__(256)
void k_agg_head(const unsigned int* __restrict__ s4, const int* __restrict__ offs,
                const int* __restrict__ cnt, const int* __restrict__ srcs,
                const float* __restrict__ dinv, const float* __restrict__ bias,
                const float* __restrict__ Wl, const float* __restrict__ bl,
                float* __restrict__ out, int n) {
  int v = (int)(((size_t)blockIdx.x * blockDim.x + threadIdx.x) >> 6);
  if (v >= n) return;
  int lane = threadIdx.x & 63;
  float4 acc = agg_core(s4, offs, cnt, srcs, v, lane);
  float p = 0.0f;
  if (lane < 32) {
    int cl = lane;
    float d = dinv[v];
    float4 bb = ((const float4*)bias)[cl];
    float4 wv = ((const float4*)Wl)[cl];
    float r0 = fmaxf(acc.x * d + bb.x, 0.0f);
    float r1 = fmaxf(acc.y * d + bb.y, 0.0f);
    float r2 = fmaxf(acc.z * d + bb.z, 0.0f);
    float r3 = fmaxf(acc.w * d + bb.w, 0.0f);
    p = r0 * wv.x + r1 * wv.y + r2 * wv.z + r3 * wv.w;
  }
  p += __shfl_down(p, 16, 64);
  p += __shfl_down(p, 8, 64);
  p += __shfl_down(p, 4, 64);
  p += __shfl_down(p, 2, 64);
  p += __shfl_down(p, 1, 64);
  if (lane == 0) {
    float z = p + bl[0];
    out[v] = 1.0f / (1.0f + expf(-z));
  }
}

// ---------------- launch ----------------

extern "C" void kernel_launch(void* const* d_in, const int* in_sizes, int n_in,
                              void* d_out, int out_size, void* d_ws, size_t ws_size,
                              hipStream_t stream) {
  const float* x  = (const float*)d_in[0];
  const int*   ei = (const int*)d_in[1];
  const float* W1 = (const float*)d_in[2];
  const float* b1 = (const float*)d_in[3];
  const float* W2 = (const float*)d_in[4];
  const float* b2 = (const float*)d_in[5];
  const float* Wl = (const float*)d_in[6];
  const float* bl = (const float*)d_in[7];
  float* out = (float*)d_out;

  int n  = in_sizes[0] / FDIM;   // 100000
  int nE = in_sizes[1] / 2;      // 3200000
  const int* row = ei;
  const int* col = ei + nE;
  int nb = (n + BKT_W - 1) >> BKT_BITS;   // 391

  // workspace carve (~53 MB); pairs aliases hb (hb first written after k_fine)
  unsigned char* s8 = (unsigned char*)d_ws;             // n*128 bytes (fp8)
  unsigned int* hb  = (unsigned int*)(s8 + (size_t)n * 128); // n*64 dwords (bf16x2)
  float* dinv  = (float*)(hb + (size_t)n * 64);         // n
  int*   cnt   = (int*)(dinv + n);                      // n
  int*   offs  = cnt + n;                               // n
  int*   srcs  = offs + n;                              // nE
  int*   gbcnt = srcs + nE;                             // nb
  int*   gboff = gbcnt + nb;                            // nb+1
  int*   gcur  = gboff + nb + 1;                        // nb
  int*   pairs = (int*)hb;                              // nE packed (aliased)

  hipMemsetAsync(gbcnt, 0, (size_t)nb * sizeof(int), stream);
  k_bhist<<<1024, 256, 0, stream>>>(col, gbcnt, nE, nb);
  k_bscan<<<1, 512, 0, stream>>>(gbcnt, gboff, gcur, nb, nE);
  int chunk = (nE + 511) / 512;   // 6250 <= BIN_CHUNK
  k_bin<<<512, 256, 0, stream>>>(row, col, gcur, pairs, nE, chunk, nb);
  k_fine<<<nb, 1024, 0, stream>>>(pairs, gboff, srcs, offs, cnt, dinv, n);

  int gemm_grid = (n + 63) / 64;  // 64 rows per block (4 waves x 16 rows)
  int wave_grid = (n + 3) / 4;    // 4 waves / 256-thread block
  k_gemm_mfma_f<<<gemm_grid, 256, 0, stream>>>(x, W1, dinv, s8, n);
  k_agg_mid<<<wave_grid, 256, 0, stream>>>((const unsigned int*)s8, offs, cnt, srcs, dinv, b1, hb, n);
  k_gemm_mfma_b<<<gemm_grid, 256, 0, stream>>>(hb, W2, dinv, s8, n);
  k_agg_head<<<wave_grid, 256, 0, stream>>>((const unsigned int*)s8, offs, cnt, srcs, dinv, b2, Wl, bl, out, n);
}